// Round 2
// baseline (376.631 us; speedup 1.0000x reference)
//
#include <hip/hip_runtime.h>
#include <math.h>

// Problem constants
#define DIMD 512
#define QS 64
#define KS 256
#define WIN 4
#define BATCH 8
#define RANK 32
#define NQ 1024             // q tokens per batch
#define NK 4096             // kv tokens per batch
#define MQ (BATCH*NQ)       // 8192 q rows
#define MK (BATCH*NK)       // 32768 kv rows

typedef unsigned short u16;
typedef __attribute__((ext_vector_type(8))) short bf16x8;  // MFMA A/B frag (8 bf16)
typedef __attribute__((ext_vector_type(4))) float f32x4;   // MFMA C/D frag

__device__ inline u16 f2bf(float x) {
    union { float f; unsigned int u; } v; v.f = x;
    unsigned int r = v.u + 0x7FFF + ((v.u >> 16) & 1);
    return (u16)(r >> 16);
}
__device__ inline float bf2f(u16 x) {
    union { unsigned int u; float f; } v; v.u = ((unsigned int)x) << 16;
    return v.f;
}

// async global->LDS, 16 B per lane. LDS dest = wave-uniform base + lane*16.
__device__ __forceinline__ void gload16(const u16* g, u16* l) {
    __builtin_amdgcn_global_load_lds(
        (const __attribute__((address_space(1))) void*)g,
        (__attribute__((address_space(3))) void*)l, 16, 0, 0);
}

// ===========================================================================
// Device bodies
// ===========================================================================

// norm: LN(source)*g+b -> bf16. One wave handles 8 rows, all 16 float4 loads
// issued upfront (256 B/lane in flight), shuffle levels interleaved across rows.
__device__ __forceinline__ void norm0_body8(
    int widx, const float* __restrict__ X, const float* __restrict__ g,
    const float* __restrict__ bb, u16* __restrict__ out)
{
    int lane = threadIdx.x & 63;
    long row0 = (long)widx * 8;
    int c = lane * 8;
    float4 a[8], b[8];
    #pragma unroll
    for (int i = 0; i < 8; i++) {
        const float* x = X + (row0 + i) * DIMD + c;
        a[i] = *(const float4*)x;
        b[i] = *(const float4*)(x + 4);
    }
    float s[8], ss[8];
    #pragma unroll
    for (int i = 0; i < 8; i++) {
        s[i]  = a[i].x + a[i].y + a[i].z + a[i].w + b[i].x + b[i].y + b[i].z + b[i].w;
        ss[i] = a[i].x*a[i].x + a[i].y*a[i].y + a[i].z*a[i].z + a[i].w*a[i].w
              + b[i].x*b[i].x + b[i].y*b[i].y + b[i].z*b[i].z + b[i].w*b[i].w;
    }
    #pragma unroll
    for (int o = 1; o < 64; o <<= 1) {
        #pragma unroll
        for (int i = 0; i < 8; i++) {
            s[i]  += __shfl_xor(s[i], o);
            ss[i] += __shfl_xor(ss[i], o);
        }
    }
    float4 g0 = *(const float4*)&g[c],  g1 = *(const float4*)&g[c + 4];
    float4 b0 = *(const float4*)&bb[c], b1 = *(const float4*)&bb[c + 4];
    #pragma unroll
    for (int i = 0; i < 8; i++) {
        float mu = s[i] * (1.f / DIMD);
        float var = ss[i] * (1.f / DIMD) - mu * mu;
        float rs = rsqrtf(var + 1e-5f);
        u16 o8[8];
        o8[0] = f2bf((a[i].x - mu) * rs * g0.x + b0.x);
        o8[1] = f2bf((a[i].y - mu) * rs * g0.y + b0.y);
        o8[2] = f2bf((a[i].z - mu) * rs * g0.z + b0.z);
        o8[3] = f2bf((a[i].w - mu) * rs * g0.w + b0.w);
        o8[4] = f2bf((b[i].x - mu) * rs * g1.x + b1.x);
        o8[5] = f2bf((b[i].y - mu) * rs * g1.y + b1.y);
        o8[6] = f2bf((b[i].z - mu) * rs * g1.z + b1.z);
        o8[7] = f2bf((b[i].w - mu) * rs * g1.w + b1.w);
        *(int4*)&out[(row0 + i) * DIMD + c] = *(const int4*)o8;
    }
}

// row stats for query rows: mu, rstd. One wave handles 8 rows, upfront loads.
__device__ __forceinline__ void stats_body8(
    int widx, const float* __restrict__ X, float* __restrict__ mu_o, float* __restrict__ rs_o)
{
    int lane = threadIdx.x & 63;
    long row0 = (long)widx * 8;
    int c = lane * 8;
    float4 a[8], b[8];
    #pragma unroll
    for (int i = 0; i < 8; i++) {
        const float* x = X + (row0 + i) * DIMD + c;
        a[i] = *(const float4*)x;
        b[i] = *(const float4*)(x + 4);
    }
    float s[8], ss[8];
    #pragma unroll
    for (int i = 0; i < 8; i++) {
        s[i]  = a[i].x + a[i].y + a[i].z + a[i].w + b[i].x + b[i].y + b[i].z + b[i].w;
        ss[i] = a[i].x*a[i].x + a[i].y*a[i].y + a[i].z*a[i].z + a[i].w*a[i].w
              + b[i].x*b[i].x + b[i].y*b[i].y + b[i].z*b[i].z + b[i].w*b[i].w;
    }
    #pragma unroll
    for (int o = 1; o < 64; o <<= 1) {
        #pragma unroll
        for (int i = 0; i < 8; i++) {
            s[i]  += __shfl_xor(s[i], o);
            ss[i] += __shfl_xor(ss[i], o);
        }
    }
    if (lane < 8) {
        int i = lane;
        float mu = s[i] * (1.f / DIMD);
        float var = ss[i] * (1.f / DIMD) - mu * mu;
        mu_o[row0 + i] = mu;
        rs_o[row0 + i] = rsqrtf(var + 1e-5f);
    }
}

// film_h: h = silu(ctx0@Wc0 + bc0 + ctx1@Wc1 + bc1), bid in [0,64)
__device__ __forceinline__ void film_h_body(
    int bid, const float* __restrict__ ctx0, const float* __restrict__ ctx1,
    const float* __restrict__ Wc0, const float* __restrict__ bc0,
    const float* __restrict__ Wc1, const float* __restrict__ bc1,
    float* __restrict__ h)
{
    int b = bid >> 3;
    int d0 = (bid & 7) * 64;
    int t = threadIdx.x;
    int dl = t >> 2, p = t & 3;
    int d = d0 + dl;
    const float* c0 = ctx0 + b * DIMD;
    const float* c1 = ctx1 + b * DIMD;
    float acc = 0.f;
    #pragma unroll 4
    for (int ii = 0; ii < 128; ii++) {
        int i = p * 128 + ii;
        acc = fmaf(c0[i], Wc0[i * DIMD + d], acc);
        acc = fmaf(c1[i], Wc1[i * DIMD + d], acc);
    }
    acc += __shfl_xor(acc, 1);
    acc += __shfl_xor(acc, 2);
    if (p == 0) {
        float v = acc + bc0[d] + bc1[d];
        h[b * DIMD + d] = v / (1.f + expf(-v));
    }
}

// film_gb: gamma,beta = split(h @ Wf + bf), bid in [0,64)
__device__ __forceinline__ void film_gb_body(
    int bid, const float* __restrict__ h, const float* __restrict__ Wf,
    const float* __restrict__ bfv, float* __restrict__ gamma, float* __restrict__ beta)
{
    int b = bid >> 3;
    int d0 = (bid & 7) * 64;
    int t = threadIdx.x;
    int dl = t >> 2, p = t & 3;
    int d = d0 + dl;
    const float* hb = h + b * DIMD;
    float ga = 0.f, be = 0.f;
    #pragma unroll 4
    for (int ii = 0; ii < 128; ii++) {
        int i = p * 128 + ii;
        float hv = hb[i];
        ga = fmaf(hv, Wf[i * 2 * DIMD + d], ga);
        be = fmaf(hv, Wf[i * 2 * DIMD + DIMD + d], be);
    }
    ga += __shfl_xor(ga, 1); ga += __shfl_xor(ga, 2);
    be += __shfl_xor(be, 1); be += __shfl_xor(be, 2);
    if (p == 0) {
        gamma[b * DIMD + d] = ga + bfv[d];
        beta[b * DIMD + d]  = be + bfv[DIMD + d];
    }
}

// transpose W[512][512] -> bf16 dst[dst_row_off + n][k], i in [0,256)
__device__ __forceinline__ void transpose_body(
    int i, const float* __restrict__ src, u16* __restrict__ dst, int dst_row_off,
    float (*tile)[33])
{
    int t = threadIdx.x;
    int tx = t & 31, ty = t >> 5;
    int bx = (i & 15) * 32;
    int by = (i >> 4) * 32;
    #pragma unroll
    for (int k = 0; k < 4; k++)
        tile[ty + k * 8][tx] = src[(long)(by + ty + k * 8) * DIMD + bx + tx];
    __syncthreads();
    #pragma unroll
    for (int k = 0; k < 4; k++)
        dst[(long)(dst_row_off + bx + ty + k * 8) * DIMD + by + tx] = f2bf(tile[tx][ty + k * 8]);
}

// gatefuse: dst[off+r][k] = sum_j W[k][j]*Wg[j][r], idx = global elem id
__device__ __forceinline__ void gatefuse_body(
    int idx, const float* __restrict__ W, const float* __restrict__ Wg,
    u16* __restrict__ dst, int dst_row_off)
{
    int r = idx & 31, k = idx >> 5;
    float acc = 0.f;
    #pragma unroll 4
    for (int j = 0; j < DIMD; j++) acc = fmaf(W[k * DIMD + j], Wg[j * RANK + r], acc);
    dst[(long)(dst_row_off + r) * DIMD + k] = f2bf(acc);
}

__device__ __forceinline__ void biascat3_body(
    int bid, const float* __restrict__ b0, const float* __restrict__ b1,
    const float* __restrict__ Wg, float* __restrict__ dst)
{
    int t = bid * 256 + threadIdx.x;
    if (t < 512) dst[t] = b0[t];
    else if (t < 1024) dst[t] = b1[t - 512];
    else if (t < 1056) {
        int r = t - 1024;
        float a = 0.f;
        #pragma unroll 4
        for (int j = 0; j < DIMD; j++) a = fmaf(b0[j], Wg[j * RANK + r], a);
        dst[t] = a;
    }
}

__device__ __forceinline__ void biascat2_body(
    int bid, const float* __restrict__ b0, const float* __restrict__ Wg,
    float* __restrict__ dst)
{
    int t = bid * 256 + threadIdx.x;
    if (t < 512) dst[t] = b0[t];
    else if (t < 544) {
        int r = t - 512;
        float a = 0.f;
        #pragma unroll 4
        for (int j = 0; j < DIMD; j++) a = fmaf(b0[j], Wg[j * RANK + r], a);
        dst[t] = a;
    }
}

// ---------------------------------------------------------------------------
// bf16 MFMA GEMM body (m97 structure), id = logical block index
// ---------------------------------------------------------------------------
template<int NSEC, bool BF>
__device__ __forceinline__ void gemm_body(
    int id, const u16* __restrict__ A, const u16* __restrict__ Bt,
    const float* __restrict__ biascat,
    void* __restrict__ C0v, void* __restrict__ C1v, void* __restrict__ Cgv,
    int Nvalid, int nx, int ypg, u16* smem)
{
    u16* As = smem;
    u16* Bs = smem + 4096;

    int t = threadIdx.x;
    int wave = t >> 6, lane = t & 63;
    int xcd = id & 7, li = id >> 3;
    int by = xcd * ypg + li / nx;
    int bx = li % nx;
    int m0 = by * 128, n0 = bx * 128;
    int mhalf = (wave >> 1) * 64, nhalf = (wave & 1) * 64;
    int lm = lane & 15, quad = lane >> 4;

    int srow = wave * 32 + (lane >> 2);
    int scol = (lane & 3) * 8;
    const u16* Ag = A + (long)(m0 + srow) * DIMD + scol;
    const u16* Bg = Bt + (long)(n0 + srow) * DIMD + scol;
    u16* Asl = As + wave * 1024 + lane * 8;
    u16* Bsl = Bs + wave * 1024 + lane * 8;

    f32x4 acc[4][4];
    #pragma unroll
    for (int i = 0; i < 4; i++)
        #pragma unroll
        for (int j = 0; j < 4; j++)
            acc[i][j] = (f32x4){0.f, 0.f, 0.f, 0.f};

    for (int k0 = 0; k0 < DIMD; k0 += 32) {
        __syncthreads();
        gload16(Ag + k0, Asl);
        gload16(Ag + 16 * DIMD + k0, Asl + 512);
        gload16(Bg + k0, Bsl);
        gload16(Bg + 16 * DIMD + k0, Bsl + 512);
        __syncthreads();
        bf16x8 af[4], bfr[4];
        #pragma unroll
        for (int i = 0; i < 4; i++) {
            af[i]  = *(const bf16x8*)&As[(mhalf + i * 16 + lm) * 32 + quad * 8];
            bfr[i] = *(const bf16x8*)&Bs[(nhalf + i * 16 + lm) * 32 + quad * 8];
        }
        #pragma unroll
        for (int i = 0; i < 4; i++)
            #pragma unroll
            for (int j = 0; j < 4; j++)
                acc[i][j] = __builtin_amdgcn_mfma_f32_16x16x32_bf16(af[i], bfr[j], acc[i][j], 0, 0, 0);
    }

    float biasj[4];
    #pragma unroll
    for (int j = 0; j < 4; j++) biasj[j] = biascat[n0 + nhalf + j * 16 + lm];

    if (BF) {
        for (int i = 0; i < 4; i++) {
            __syncthreads();
            #pragma unroll
            for (int j = 0; j < 4; j++)
                #pragma unroll
                for (int r = 0; r < 4; r++)
                    smem[((wave >> 1) * 16 + quad * 4 + r) * 128 + nhalf + j * 16 + lm] =
                        f2bf(acc[i][j][r] + biasj[j]);
            __syncthreads();
            #pragma unroll
            for (int u = 0; u < 2; u++) {
                int cch = t + u * 256;
                int R = cch >> 4, ci = cch & 15;
                long grow = m0 + (R >> 4) * 64 + i * 16 + (R & 15);
                int gcol = n0 + ci * 8;
                int4 val = *(const int4*)&smem[R * 128 + ci * 8];
                if (NSEC == 1) {
                    *(int4*)((u16*)C0v + grow * 512 + gcol) = val;
                } else if (NSEC == 2) {
                    if (gcol < 512)          *(int4*)((u16*)C0v + grow * 512 + gcol) = val;
                    else if (gcol < Nvalid)  *(int4*)((u16*)Cgv + grow * 32 + (gcol - 512)) = val;
                } else {
                    if (gcol < 512)          *(int4*)((u16*)C0v + grow * 512 + gcol) = val;
                    else if (gcol < 1024)    *(int4*)((u16*)C1v + grow * 512 + (gcol - 512)) = val;
                    else if (gcol < Nvalid)  *(int4*)((u16*)Cgv + grow * 32 + (gcol - 1024)) = val;
                }
            }
        }
    } else {
        float* Stg = (float*)smem;
        for (int i = 0; i < 4; i++) {
            __syncthreads();
            #pragma unroll
            for (int j = 0; j < 4; j++)
                #pragma unroll
                for (int r = 0; r < 4; r++)
                    Stg[((wave >> 1) * 16 + quad * 4 + r) * 128 + nhalf + j * 16 + lm] =
                        acc[i][j][r] + biasj[j];
            __syncthreads();
            #pragma unroll
            for (int u = 0; u < 4; u++) {
                int cch = t + u * 256;
                int R = cch >> 5, ci = cch & 31;
                long grow = m0 + (R >> 4) * 64 + i * 16 + (R & 15);
                int gcol = n0 + ci * 4;
                *(float4*)((float*)C0v + grow * 512 + gcol) = *(const float4*)&Stg[R * 128 + ci * 4];
            }
        }
    }
}

// ===========================================================================
// K1a: prep_w — weight-space / latency-chain work.
//   [0,64)        film_h
//   [64,192)      gatefuse
//   [192,200)     biascat
//   [200,1224)    transposes
// ===========================================================================
#define PW_FILMH   64
#define PW_GATE    (PW_FILMH + 128)    // 192
#define PW_BIAS    (PW_GATE + 8)       // 200
#define PW_TOTAL   (PW_BIAS + 1024)    // 1224

__global__ __launch_bounds__(256) void prep_w_kernel(
    const float* __restrict__ ctx0, const float* __restrict__ ctx1,
    const float* __restrict__ Wc0, const float* __restrict__ bc0,
    const float* __restrict__ Wc1, const float* __restrict__ bc1,
    float* __restrict__ h,
    const float* __restrict__ Wk, const float* __restrict__ Wv,
    const float* __restrict__ Wq, const float* __restrict__ Wo,
    u16* __restrict__ Btkv, u16* __restrict__ Btq, u16* __restrict__ Bto,
    const float* __restrict__ Wgk, const float* __restrict__ Wgq,
    const float* __restrict__ bk, const float* __restrict__ bv,
    const float* __restrict__ bq, float* __restrict__ biaskv,
    float* __restrict__ biasq)
{
    __shared__ float tile[32][33];
    int bid = blockIdx.x;
    if (bid < PW_FILMH) {
        film_h_body(bid, ctx0, ctx1, Wc0, bc0, Wc1, bc1, h);
    } else if (bid < PW_GATE) {
        int gid = bid - PW_FILMH;
        int idx = (gid & 63) * 256 + threadIdx.x;
        if (gid < 64) gatefuse_body(idx, Wk, Wgk, Btkv, 1024);
        else          gatefuse_body(idx, Wq, Wgq, Btq, 512);
    } else if (bid < PW_BIAS) {
        int cid = bid - PW_GATE;
        if (cid < 5) biascat3_body(cid, bk, bv, Wgk, biaskv);
        else         biascat2_body(cid - 5, bq, Wgq, biasq);
    } else {
        int tid = bid - PW_BIAS;
        int which = tid >> 8, i = tid & 255;
        if (which == 0)      transpose_body(i, Wk, Btkv, 0, tile);
        else if (which == 1) transpose_body(i, Wv, Btkv, 512, tile);
        else if (which == 2) transpose_body(i, Wq, Btq, 0, tile);
        else                 transpose_body(i, Wo, Bto, 0, tile);
    }
}

// ===========================================================================
// K1b: prep_s — streaming work (stats + norm0), 8 rows/wave.
//   [0,256)       q stats   (8 rows/wave)
//   [256,1280)    norm0     (8 rows/wave)
// ===========================================================================
#define PS_STATS   256
#define PS_TOTAL   (PS_STATS + 1024)   // 1280

__global__ __launch_bounds__(256) void prep_s_kernel(
    const float* __restrict__ source, const float* __restrict__ kvn_g,
    const float* __restrict__ kvn_b, u16* __restrict__ sln,
    const float* __restrict__ query, float* __restrict__ mu_q, float* __restrict__ rs_q)
{
    int bid = blockIdx.x;
    int wave = threadIdx.x >> 6;
    if (bid < PS_STATS) {
        stats_body8(bid * 4 + wave, query, mu_q, rs_q);
    } else {
        norm0_body8((bid - PS_STATS) * 4 + wave, source, kvn_g, kvn_b, sln);
    }
}

// ===========================================================================
// K2: film_gb (64 blocks) + kv projection GEMM (2304 blocks)
// ===========================================================================
__global__ __launch_bounds__(256) void kv_kernel(
    const float* __restrict__ h, const float* __restrict__ Wf,
    const float* __restrict__ bfv, float* __restrict__ gamma, float* __restrict__ beta,
    const u16* __restrict__ sln, const u16* __restrict__ Btkv,
    const float* __restrict__ biaskv,
    u16* __restrict__ kp, u16* __restrict__ vp, u16* __restrict__ gk)
{
    __shared__ u16 smem[8192];
    int bid = blockIdx.x;
    if (bid < 64) {
        film_gb_body(bid, h, Wf, bfv, gamma, beta);
    } else {
        gemm_body<3, true>(bid - 64, sln, Btkv, biaskv, kp, vp, gk, 1056, 9, 32, smem);
    }
}

// ===========================================================================
// K3: q projection GEMM with LN+FiLM fused into A-staging
// ===========================================================================
__global__ __launch_bounds__(256) void qproj_kernel(
    const float* __restrict__ query, const float* __restrict__ mu_q,
    const float* __restrict__ rs_q, const float* __restrict__ qn_g,
    const float* __restrict__ qn_b, const float* __restrict__ gamma,
    const float* __restrict__ beta, const u16* __restrict__ Btq,
    const float* __restrict__ biasq, u16* __restrict__ qp, u16* __restrict__ gq)
{
    __shared__ u16 smem[8192];
    u16* As = smem;
    u16* Bs = smem + 4096;

    int t = threadIdx.x;
    int wave = t >> 6, lane = t & 63;
    int id = blockIdx.x;
    int xcd = id & 7, li = id >> 3;
    int by = xcd * 8 + li / 5;
    int bx = li % 5;
    int m0 = by * 128, n0 = bx * 128;
    int mhalf = (wave >> 1) * 64, nhalf = (wave & 1) * 64;
    int lm = lane & 15, quad = lane >> 4;
    int bt = m0 >> 10;                    // batch (128 | 1024, uniform per block)

    int srow = wave * 32 + (lane >> 2);
    int scol = (lane & 3) * 8;
    const u16* Bg = Btq + (long)(n0 + srow) * DIMD + scol;
    u16* Bsl = Bs + wave * 1024 + lane * 8;

    f32x4 acc[4][4];
    #pragma unroll
    for (int i = 0; i < 4; i++)
        #pragma unroll
        for (int j = 0; j < 4; j++)
            acc[i][j] = (f32x4){0.f, 0.f, 0.f, 0.f};

    for (int k0 = 0; k0 < DIMD; k0 += 32) {
        __syncthreads();
        gload16(Bg + k0, Bsl);
        gload16(Bg + 16 * DIMD + k0, Bsl + 512);
        // A staging: LN+FiLM inline, 2 chunks of 8 elements per thread
        #pragma unroll
        for (int u = 0; u < 2; u++) {
            int idx = t + u * 256;            // 0..511
            int r = idx >> 2;                 // row 0..127
            int c8 = (idx & 3) * 8;           // col 0,8,16,24
            long grow = m0 + r;
            int col = k0 + c8;
            const float* xp = &query[grow * DIMD + col];
            float4 x0 = *(const float4*)xp, x1 = *(const float4*)(xp + 4);
            float mu = mu_q[grow], rs = rs_q[grow];
            float4 g0 = *(const float4*)&qn_g[col], g1 = *(const float4*)&qn_g[col + 4];
            float4 b0 = *(const float4*)&qn_b[col], b1 = *(const float4*)&qn_b[col + 4];
            const float* gp = gamma + bt * DIMD + col;
            const float* bp = beta + bt * DIMD + col;
            float4 gm0 = *(const float4*)gp, gm1 = *(const float4*)(gp + 4);
            float4 be0 = *(const float4*)bp, be1 = *(const float4*)(bp + 4);
            u16 o8[8];
            o8[0] = f2bf(((x0.x - mu) * rs * g0.x + b0.x) * (1.f + gm0.x) + be0.x);
            o8[1] = f2bf(((x0.y - mu) * rs * g0.y + b0.y) * (1.f + gm0.y) + be0.y);
            o8[2] = f2bf(((x0.z - mu) * rs * g0.z + b0.z) * (1.f + gm0.z) + be0.z);
            o8[3] = f2bf(((x0.w - mu) * rs * g0.w + b0.w) * (1.f + gm0.w) + be0.w);
            o8[4] = f2bf(((x1.x - mu) * rs * g1.x + b1.x) * (1.f + gm1.x) + be1.x);
            o8[5] = f2bf(((x1.y - mu) * rs * g1.y + b1.y) * (1.f + gm1.y) + be1.y);
            o8[6] = f2bf(((x1.z - mu) * rs * g1.z + b1.z) * (1.f + gm1.z) + be1.z);
            o8[7] = f2bf(((x1.w - mu) * rs * g1.w + b1.w) * (1.f + gm1.w) + be1.w);
            *(int4*)&As[r * 32 + c8] = *(const int4*)o8;
        }
        __syncthreads();
        bf16x8 af[4], bfr[4];
        #pragma unroll
        for (int i = 0; i < 4; i++) {
            af[i]  = *(const bf16x8*)&As[(mhalf + i * 16 + lm) * 32 + quad * 8];
            bfr[i] = *(const bf16x8*)&Bs[(nhalf + i * 16 + lm) * 32 + quad * 8];
        }
        #pragma unroll
        for (int i = 0; i < 4; i++)
            #pragma unroll
            for (int j = 0; j < 4; j++)
                acc[i][j] = __builtin_amdgcn_mfma_f32_16x16x32_bf16(af[i], bfr[j], acc[i][j], 0, 0, 0);
    }

    float biasj[4];
    #pragma unroll
    for (int j = 0; j < 4; j++) biasj[j] = biasq[n0 + nhalf + j * 16 + lm];

    for (int i = 0; i < 4; i++) {
        __syncthreads();
        #pragma unroll
        for (int j = 0; j < 4; j++)
            #pragma unroll
            for (int r = 0; r < 4; r++)
                smem[((wave >> 1) * 16 + quad * 4 + r) * 128 + nhalf + j * 16 + lm] =
                    f2bf(acc[i][j][r] + biasj[j]);
        __syncthreads();
        #pragma unroll
        for (int u = 0; u < 2; u++) {
            int cch = t + u * 256;
            int R = cch >> 4, ci = cch & 15;
            long grow = m0 + (R >> 4) * 64 + i * 16 + (R & 15);
            int gcol = n0 + ci * 8;
            int4 val = *(const int4*)&smem[R * 128 + ci * 8];
            if (gcol < 512)       *(int4*)(qp + grow * 512 + gcol) = val;
            else if (gcol < 544)  *(int4*)(gq + grow * 32 + (gcol - 512)) = val;
        }
    }
}

// ===========================================================================
// K5: output projection (fp32 out)
// ===========================================================================
__global__ __launch_bounds__(256) void ogemm_kernel(
    const u16* __restrict__ ctxb, const u16* __restrict__ Bto,
    const float* __restrict__ bo, float* __restrict__ out)
{
    __shared__ u16 smem[8192];
    gemm_body<1, false>(blockIdx.x, ctxb, Bto, bo, out, nullptr, nullptr, 512, 4, 8, smem);
}

// ===========================================================================
// K4: Flash-style local attention (unchanged)
// ===========================================================================
__global__ __launch_bounds__(256, 2) void attn_kernel(
    const u16* __restrict__ q_bf, const u16* __restrict__ k_bf,
    const u16* __restrict__ v_bf, const u16* __restrict__ gq_bf,
    const u16* __restrict__ gk_bf, u16* __restrict__ ctx)
{
    __shared__ u16 Ks[16 * 512];
    __shared__ u16 Vt[512 * 32];
    __shared__ u16 Pb[16 * 40];
    __shared__ float part[4][16][16];
    __shared__ float Gb[16][16];
    __shared__ float alphap[16];
    __shared__ float linv[16];

    int blk = blockIdx.x;
    int b = blk >> 6, qs = blk & 63;
    int center = (int)(qs * (255.0f / 63.0f) + 0.5f);
    int lo = center - WIN; if (lo < 0) lo = 0;
    int hi = center + WIN; if (hi > KS - 1) hi = KS - 1;
    int nst = hi - lo + 1;
    long rowq0 = (long)b * NQ + qs * 16;
    long rowk0 = (long)b * NK + lo * 16;

    int t = threadIdx.x;
    int wave = t >> 6, lane = t & 63;
    int lm = lane & 15, quad = lane >> 4;
    int qi = t >> 4, ki = t & 15;

    bf16x8 qf[4];
    #pragma unroll
    for (int f = 0; f < 4; f++)
        qf[f] = *(const bf16x8*)&q_bf[(rowq0 + lm) * DIMD + wave * 128 + f * 32 + quad * 8];
    bf16x8 gqf;
    if (wave == 3) gqf = *(const bf16x8*)&gq_bf[(rowq0 + lm) * RANK + quad * 8];

    int4 kpre[4], vpre[4];
    #pragma unroll
    for (int u = 0; u < 4; u++) {
        int idx = u * 256 + t;
        kpre[u] = *(const int4*)&k_bf[(rowk0 + (idx >> 6)) * DIMD + (idx & 63) * 8];
        int vkv = (idx >> 2) & 15, vdc = (idx & 3) | ((idx >> 6) << 2);
        vpre[u] = *(const int4*)&v_bf[(rowk0 + vkv) * DIMD + vdc * 8];
    }

    float m_run = -1e30f, l_run = 0.f;
    f32x4 acc[8];
    #pragma unroll
    for (int j = 0; j < 8; j++) acc[j] = (f32x4){0.f, 0.f, 0.f, 0.f};

    const float scale = 0.044194173824159216f;   // 512^-0.5
    const float grs = 0.17677669529663687f;      // 32^-0.5

    for (int s = 0; s < nst; s++) {
        int half = s & 1;
        #pragma unroll
        for (int u = 0; u < 4; u++) {
            int idx = u * 256 + t;
            int row = idx >> 6, c = idx & 63;
            *(int4*)&Ks[row * 512 + (c ^ (row & 7)) * 8] = kpre[u];
            int vkv = (idx >> 2) & 15, vdc = (idx & 3) | ((idx >> 6) << 2);
            int kvp = half * 16 + vkv;
            u16 vv[8];
            *(int4*)vv = vpre[u];
            #pragma unroll
            for (int i = 0; i < 8; i++) {
                int d = vdc * 8 + i;
                Vt[d * 32 + (((kvp >> 3) ^ (d & 3)) << 3) + (kvp & 7)] = vv[i];
            }
        }
        __syncthreads();
        if (s + 1 < nst) {
            long rk = rowk0 + (long)(s + 1) * 16;
            #pragma unroll
            for (int u = 0; u < 4; u++) {
                int idx = u * 256 + t;
                kpre[u] = *(const int4*)&k_bf[(rk + (idx >> 6)) * DIMD + (idx & 63) * 8];
                int vkv = (idx >> 2) & 15, vdc = (idx & 3) | ((idx >> 6) << 2);
                vpre[u] = *(const int4*)&v_bf[(rk + vkv) * DIMD + vdc * 8];
            }
        }
        f32x4 sacc = (f32x4){0.f, 0.f, 0.f, 0.f};
        #pragma unroll
        for (int f = 0; f < 4; f++) {
            int cidx = wave * 16 + f * 4 + quad;
            bf16x8 kf = *(const bf16x8*)&Ks[lm * 512 + (cidx ^ (lm & 7)) * 8];
            sacc = __builtin_amdgcn_mfma_f32_16x16x32_bf16(qf[f], kf, sacc, 0, 0, 0);
        }
        #pragma unroll
        for (int r = 0; r < 4; r++) part[wave][quad * 4 + r][lm] = sacc[r];
        if (wave == 3) {
            bf16x8 gkf = *(const bf16x8*)&gk_bf[(rowk0 + (long)s * 16 + lm) * RANK + quad * 8];
            f32x4 gacc = (f32x4){0.f, 0.f, 0.f, 0.f};
            gacc = __builtin_amdgcn_mfma_f32_16x16x32_bf16(gqf, gkf, gacc, 0, 0, 0);
            #pragma unroll
            for (int r = 0; r < 4; r++) Gb[quad * 4 + r][lm] = gacc[r];
        }
        __syncthreads();
        float sv = (part[0][qi][ki] + part[1][qi][ki] + part[2][qi][ki] + part[3][qi][ki]) * scale;
        float gl = Gb[qi][ki] * grs;
        float sig = 1.f / (1.f + expf(-gl));
        sv += logf(sig + 1e-6f);
        float mx = sv;
        mx = fmaxf(mx, __shfl_xor(mx, 1));
        mx = fmaxf(mx, __shfl_xor(mx, 2));
        mx = fmaxf(mx, __shfl_xor(mx, 4));
        mx = fmaxf(mx, __shfl_xor(mx, 8));
        float m_new = fmaxf(m_run, mx);
        float p = expf(sv - m_new);
        float ps = p;
        ps += __shfl_xor(ps, 1);
        ps += __shfl_xor(ps, 2);
        ps += __shfl_xor(ps, 4);
        ps += __shfl_xor(ps, 8);
        float alpha = expf(m_run - m_new);
        l_run = l_run * alpha + ps;
        m_run = m_new;
        Pb[qi * 40 + half * 16 + ki] = f2bf(p);
        if (half == 1) {
            Pb[qi * 40 + ki] = f2bf(bf2f(Pb[qi * 40 + ki]) * alpha);
        }
        bool dopv = (half == 1) || (s == nst - 1);
        if (dopv && half == 0) Pb[qi * 40 + 16 + ki] = 0;
        if (ki == 0) {
            if (half == 0) alphap[qi] = alpha;
            else           alphap[qi] *= alpha;
            if (s == nst - 1) linv[qi] = 1.f / l_run;
        }
        __syncthreads();
        if (dopv) {
            float ar[4];
            #pragma unroll
            for (int r = 0; r < 4; r++) ar[r] = alphap[quad * 4 + r];
            #pragma unroll
            for (int j = 0; j < 8; j++)
                #pragma unroll
                for (int r = 0; r < 4; r++) acc[j][r] *= ar[r];
            bf16x8 pf = *(const bf16x8*)&Pb[lm * 40 + quad * 8];
            #pragma unroll
            for (int j = 0; j < 8; j++) {
                int d = wave * 128 + j * 16 + lm;
                bf16x8 vf = *(const bf16x8*)&Vt[d * 32 + ((quad ^ (d & 3)) << 3)];
                acc[j] = __builtin_amdgcn_mfma_f32_16x16x32_bf16(pf, vf, acc[j], 0, 0, 0);
            }
            __syncthreads();
        }
    }
    float li[4];
    #pragma unroll
    for (int r = 0; r < 4; r++) li[r] = linv[quad * 4 + r];
    #pragma unroll
    for (int j = 0; j < 8; j++) {
        int d = wave * 128 + j * 16 + lm;
        #pragma unroll
        for (int r = 0; r < 4; r++)
            ctx[(rowq0 + quad * 4 + r) * DIMD + d] = f2bf(acc[j][r] * li[r]);
    }
}

// ---------------------------------------------------------------------------
extern "C" void kernel_launch(void* const* d_in, const int* in_sizes, int n_in,
                              void* d_out, int out_size, void* d_ws, size_t ws_size,
                              hipStream_t stream) {
    const float* query  = (const float*)d_in[0];
    const float* source = (const float*)d_in[1];
    const float* ctx0   = (const float*)d_in[2];
    const float* ctx1   = (const float*)d_in[3];
    // d_in[4] = mask: structurally known local window, unused
    const float* qn_g  = (const float*)d_in[5];
    const float* qn_b  = (const float*)d_in[6];
    const float* kvn_g = (const float*)d_in[7];
    const float* kvn_b = (const float*)d_in[8];
    const float* Wq = (const float*)d_in[9];   const float* bq = (const float*)d_in[10];
    const float* Wk = (const float*)d_in[11];  const float* bk = (const float*)d_in[12];
    const float* Wv = (const float*)d_in[13];  const float* bv = (const float*)d_in[14];
    const float* Wo = (const float*)d_in[15];  const float* bo = (const float*)d_in[16];
    const float* Wgq = (const float*)d_in[17];
    const float* Wgk = (const float*)d_in[18];
    const float* Wc0 = (const float*)d_in[19]; const float* bc0 = (const float*)d_in[20];
    const float* Wc1 = (const float*)d_in[21]; const float* bc1 = (const float*)d_in[22];
    const float* Wf  = (const float*)d_in[23]; const float* bfv = (const float*)d_in[24];

    // ---- workspace layout ----
    float* ws = (float*)d_ws;
    float* h      = ws;                         // 4096
    float* gamma  = h + 4096;                   // 4096
    float* beta   = gamma + 4096;               // 4096
    float* biaskv = beta + 4096;                // 1152
    float* biasq  = biaskv + 1152;              // 640
    float* mu_q   = biasq + 640;                // 8192
    float* rs_q   = mu_q + 8192;                // 8192
    u16* u = (u16*)(rs_q + 8192);
    u16* sln  = u;                 u += (long)MK * DIMD;   // LN(source) bf16
    u16* kp   = u;                 u += (long)MK * DIMD;   // k proj bf16
    u16* vp   = u;                 u += (long)MK * DIMD;   // v proj bf16
    u16* gk   = u;                 u += (long)MK * RANK;   // gate_k bf16
    u16* gq   = u;                 u += (long)MQ * RANK;   // gate_q bf16
    u16* qp   = u;                 u += (long)MQ * DIMD;   // q proj bf16
    u16* ctxb = u;                 u += (long)MQ * DIMD;   // attention output bf16
    u16* Btkv = u;                 u += 1152L * DIMD;      // [Wk^T | Wv^T | (Wk·Wgk)^T]
    u16* Btq  = u;                 u += 640L * DIMD;       // [Wq^T | (Wq·Wgq)^T]
    u16* Bto  = u;                 u += 512L * DIMD;       // Wo^T
    float* out = (float*)d_out;

    // K1a: weight-space prep (latency chains)
    prep_w_kernel<<<PW_TOTAL, 256, 0, stream>>>(
        ctx0, ctx1, Wc0, bc0, Wc1, bc1, h,
        Wk, Wv, Wq, Wo, Btkv, Btq, Bto,
        Wgk, Wgq, bk, bv, bq, biaskv, biasq);

    // K1b: streaming prep (stats + norm0)
    prep_s_kernel<<<PS_TOTAL, 256, 0, stream>>>(
        source, kvn_g, kvn_b, sln, query, mu_q, rs_q);

    // K2: film_gb + kv projection GEMM
    kv_kernel<<<64 + 2304, 256, 0, stream>>>(
        h, Wf, bfv, gamma, beta, sln, Btkv, biaskv, kp, vp, gk);

    // K3: q projection GEMM (LN+FiLM inline)
    qproj_kernel<<<320, 256, 0, stream>>>(
        query, mu_q, rs_q, qn_g, qn_b, gamma, beta, Btq, biasq, qp, gq);

    // K4: flash local attention
    attn_kernel<<<BATCH * QS, 256, 0, stream>>>(qp, kp, vp, gq, gk, ctxb);

    // K5: output projection (fp32 out)
    ogemm_kernel<<<256, 256, 0, stream>>>(ctxb, Bto, bo, out);
}

// Round 3
// 368.970 us; speedup vs baseline: 1.0208x; 1.0208x over previous
//
#include <hip/hip_runtime.h>
#include <math.h>

// Problem constants
#define DIMD 512
#define QS 64
#define KS 256
#define WIN 4
#define BATCH 8
#define RANK 32
#define NQ 1024             // q tokens per batch
#define NK 4096             // kv tokens per batch
#define MQ (BATCH*NQ)       // 8192 q rows
#define MK (BATCH*NK)       // 32768 kv rows

typedef unsigned short u16;
typedef __attribute__((ext_vector_type(8))) short bf16x8;  // MFMA A/B frag (8 bf16)
typedef __attribute__((ext_vector_type(4))) float f32x4;   // MFMA C/D frag

__device__ inline u16 f2bf(float x) {
    union { float f; unsigned int u; } v; v.f = x;
    unsigned int r = v.u + 0x7FFF + ((v.u >> 16) & 1);
    return (u16)(r >> 16);
}
__device__ inline float bf2f(u16 x) {
    union { unsigned int u; float f; } v; v.u = ((unsigned int)x) << 16;
    return v.f;
}

// async global->LDS, 16 B per lane. LDS dest = wave-uniform base + lane*16.
__device__ __forceinline__ void gload16(const u16* g, u16* l) {
    __builtin_amdgcn_global_load_lds(
        (const __attribute__((address_space(1))) void*)g,
        (__attribute__((address_space(3))) void*)l, 16, 0, 0);
}

// ===========================================================================
// Device bodies
// ===========================================================================

// norm: LN(source)*g+b -> bf16. One wave handles 8 rows, all 16 float4 loads
// issued upfront (256 B/lane in flight), shuffle levels interleaved across rows.
__device__ __forceinline__ void norm0_body8(
    int widx, const float* __restrict__ X, const float* __restrict__ g,
    const float* __restrict__ bb, u16* __restrict__ out)
{
    int lane = threadIdx.x & 63;
    long row0 = (long)widx * 8;
    int c = lane * 8;
    float4 a[8], b[8];
    #pragma unroll
    for (int i = 0; i < 8; i++) {
        const float* x = X + (row0 + i) * DIMD + c;
        a[i] = *(const float4*)x;
        b[i] = *(const float4*)(x + 4);
    }
    float s[8], ss[8];
    #pragma unroll
    for (int i = 0; i < 8; i++) {
        s[i]  = a[i].x + a[i].y + a[i].z + a[i].w + b[i].x + b[i].y + b[i].z + b[i].w;
        ss[i] = a[i].x*a[i].x + a[i].y*a[i].y + a[i].z*a[i].z + a[i].w*a[i].w
              + b[i].x*b[i].x + b[i].y*b[i].y + b[i].z*b[i].z + b[i].w*b[i].w;
    }
    #pragma unroll
    for (int o = 1; o < 64; o <<= 1) {
        #pragma unroll
        for (int i = 0; i < 8; i++) {
            s[i]  += __shfl_xor(s[i], o);
            ss[i] += __shfl_xor(ss[i], o);
        }
    }
    float4 g0 = *(const float4*)&g[c],  g1 = *(const float4*)&g[c + 4];
    float4 b0 = *(const float4*)&bb[c], b1 = *(const float4*)&bb[c + 4];
    #pragma unroll
    for (int i = 0; i < 8; i++) {
        float mu = s[i] * (1.f / DIMD);
        float var = ss[i] * (1.f / DIMD) - mu * mu;
        float rs = rsqrtf(var + 1e-5f);
        u16 o8[8];
        o8[0] = f2bf((a[i].x - mu) * rs * g0.x + b0.x);
        o8[1] = f2bf((a[i].y - mu) * rs * g0.y + b0.y);
        o8[2] = f2bf((a[i].z - mu) * rs * g0.z + b0.z);
        o8[3] = f2bf((a[i].w - mu) * rs * g0.w + b0.w);
        o8[4] = f2bf((b[i].x - mu) * rs * g1.x + b1.x);
        o8[5] = f2bf((b[i].y - mu) * rs * g1.y + b1.y);
        o8[6] = f2bf((b[i].z - mu) * rs * g1.z + b1.z);
        o8[7] = f2bf((b[i].w - mu) * rs * g1.w + b1.w);
        *(int4*)&out[(row0 + i) * DIMD + c] = *(const int4*)o8;
    }
}

// row stats for query rows: mu, rstd. One wave handles 8 rows, upfront loads.
__device__ __forceinline__ void stats_body8(
    int widx, const float* __restrict__ X, float* __restrict__ mu_o, float* __restrict__ rs_o)
{
    int lane = threadIdx.x & 63;
    long row0 = (long)widx * 8;
    int c = lane * 8;
    float4 a[8], b[8];
    #pragma unroll
    for (int i = 0; i < 8; i++) {
        const float* x = X + (row0 + i) * DIMD + c;
        a[i] = *(const float4*)x;
        b[i] = *(const float4*)(x + 4);
    }
    float s[8], ss[8];
    #pragma unroll
    for (int i = 0; i < 8; i++) {
        s[i]  = a[i].x + a[i].y + a[i].z + a[i].w + b[i].x + b[i].y + b[i].z + b[i].w;
        ss[i] = a[i].x*a[i].x + a[i].y*a[i].y + a[i].z*a[i].z + a[i].w*a[i].w
              + b[i].x*b[i].x + b[i].y*b[i].y + b[i].z*b[i].z + b[i].w*b[i].w;
    }
    #pragma unroll
    for (int o = 1; o < 64; o <<= 1) {
        #pragma unroll
        for (int i = 0; i < 8; i++) {
            s[i]  += __shfl_xor(s[i], o);
            ss[i] += __shfl_xor(ss[i], o);
        }
    }
    if (lane < 8) {
        int i = lane;
        float mu = s[i] * (1.f / DIMD);
        float var = ss[i] * (1.f / DIMD) - mu * mu;
        mu_o[row0 + i] = mu;
        rs_o[row0 + i] = rsqrtf(var + 1e-5f);
    }
}

// film_h: h = silu(ctx0@Wc0 + bc0 + ctx1@Wc1 + bc1), bid in [0,64)
__device__ __forceinline__ void film_h_body(
    int bid, const float* __restrict__ ctx0, const float* __restrict__ ctx1,
    const float* __restrict__ Wc0, const float* __restrict__ bc0,
    const float* __restrict__ Wc1, const float* __restrict__ bc1,
    float* __restrict__ h)
{
    int b = bid >> 3;
    int d0 = (bid & 7) * 64;
    int t = threadIdx.x;
    int dl = t >> 2, p = t & 3;
    int d = d0 + dl;
    const float* c0 = ctx0 + b * DIMD;
    const float* c1 = ctx1 + b * DIMD;
    float acc = 0.f;
    #pragma unroll 4
    for (int ii = 0; ii < 128; ii++) {
        int i = p * 128 + ii;
        acc = fmaf(c0[i], Wc0[i * DIMD + d], acc);
        acc = fmaf(c1[i], Wc1[i * DIMD + d], acc);
    }
    acc += __shfl_xor(acc, 1);
    acc += __shfl_xor(acc, 2);
    if (p == 0) {
        float v = acc + bc0[d] + bc1[d];
        h[b * DIMD + d] = v / (1.f + expf(-v));
    }
}

// film_gb: gamma,beta = split(h @ Wf + bf), bid in [0,64)
__device__ __forceinline__ void film_gb_body(
    int bid, const float* __restrict__ h, const float* __restrict__ Wf,
    const float* __restrict__ bfv, float* __restrict__ gamma, float* __restrict__ beta)
{
    int b = bid >> 3;
    int d0 = (bid & 7) * 64;
    int t = threadIdx.x;
    int dl = t >> 2, p = t & 3;
    int d = d0 + dl;
    const float* hb = h + b * DIMD;
    float ga = 0.f, be = 0.f;
    #pragma unroll 4
    for (int ii = 0; ii < 128; ii++) {
        int i = p * 128 + ii;
        float hv = hb[i];
        ga = fmaf(hv, Wf[i * 2 * DIMD + d], ga);
        be = fmaf(hv, Wf[i * 2 * DIMD + DIMD + d], be);
    }
    ga += __shfl_xor(ga, 1); ga += __shfl_xor(ga, 2);
    be += __shfl_xor(be, 1); be += __shfl_xor(be, 2);
    if (p == 0) {
        gamma[b * DIMD + d] = ga + bfv[d];
        beta[b * DIMD + d]  = be + bfv[DIMD + d];
    }
}

// transpose W[512][512] -> bf16 dst[dst_row_off + n][k], i in [0,256)
__device__ __forceinline__ void transpose_body(
    int i, const float* __restrict__ src, u16* __restrict__ dst, int dst_row_off,
    float (*tile)[33])
{
    int t = threadIdx.x;
    int tx = t & 31, ty = t >> 5;
    int bx = (i & 15) * 32;
    int by = (i >> 4) * 32;
    #pragma unroll
    for (int k = 0; k < 4; k++)
        tile[ty + k * 8][tx] = src[(long)(by + ty + k * 8) * DIMD + bx + tx];
    __syncthreads();
    #pragma unroll
    for (int k = 0; k < 4; k++)
        dst[(long)(dst_row_off + bx + ty + k * 8) * DIMD + by + tx] = f2bf(tile[tx][ty + k * 8]);
}

// gatefuse: dst[off+r][k] = sum_j W[k][j]*Wg[j][r], idx = global elem id
__device__ __forceinline__ void gatefuse_body(
    int idx, const float* __restrict__ W, const float* __restrict__ Wg,
    u16* __restrict__ dst, int dst_row_off)
{
    int r = idx & 31, k = idx >> 5;
    float acc = 0.f;
    #pragma unroll 4
    for (int j = 0; j < DIMD; j++) acc = fmaf(W[k * DIMD + j], Wg[j * RANK + r], acc);
    dst[(long)(dst_row_off + r) * DIMD + k] = f2bf(acc);
}

__device__ __forceinline__ void biascat3_body(
    int bid, const float* __restrict__ b0, const float* __restrict__ b1,
    const float* __restrict__ Wg, float* __restrict__ dst)
{
    int t = bid * 256 + threadIdx.x;
    if (t < 512) dst[t] = b0[t];
    else if (t < 1024) dst[t] = b1[t - 512];
    else if (t < 1056) {
        int r = t - 1024;
        float a = 0.f;
        #pragma unroll 4
        for (int j = 0; j < DIMD; j++) a = fmaf(b0[j], Wg[j * RANK + r], a);
        dst[t] = a;
    }
}

__device__ __forceinline__ void biascat2_body(
    int bid, const float* __restrict__ b0, const float* __restrict__ Wg,
    float* __restrict__ dst)
{
    int t = bid * 256 + threadIdx.x;
    if (t < 512) dst[t] = b0[t];
    else if (t < 544) {
        int r = t - 512;
        float a = 0.f;
        #pragma unroll 4
        for (int j = 0; j < DIMD; j++) a = fmaf(b0[j], Wg[j * RANK + r], a);
        dst[t] = a;
    }
}

// ---------------------------------------------------------------------------
// bf16 MFMA GEMM body, BK=64 (8 K-iters, half the barrier drains of BK=32),
// merged padded epilogue. smem must be 16384 u16 (32 KB).
// ---------------------------------------------------------------------------
template<int NSEC, bool BF>
__device__ __forceinline__ void gemm_body(
    int id, const u16* __restrict__ A, const u16* __restrict__ Bt,
    const float* __restrict__ biascat,
    void* __restrict__ C0v, void* __restrict__ C1v, void* __restrict__ Cgv,
    int Nvalid, int nx, int ypg, u16* smem)
{
    u16* As = smem;           // [128][64] bf16
    u16* Bs = smem + 8192;    // [128][64] bf16

    int t = threadIdx.x;
    int wave = t >> 6, lane = t & 63;
    int xcd = id & 7, li = id >> 3;
    int by = xcd * ypg + li / nx;
    int bx = li % nx;
    int m0 = by * 128, n0 = bx * 128;
    int mhalf = (wave >> 1) * 64, nhalf = (wave & 1) * 64;
    int lm = lane & 15, quad = lane >> 4;

    // staging: per gload g, wave w covers rows g*32 + w*8 + (lane>>3),
    // cols (lane&7)*8 .. +8. LDS dest linear per wave.
    int srow = wave * 8 + (lane >> 3);
    int scol = (lane & 7) * 8;
    const u16* Ag = A + (long)(m0 + srow) * DIMD + scol;
    const u16* Bg = Bt + (long)(n0 + srow) * DIMD + scol;
    u16* Asl = As + wave * 512 + lane * 8;
    u16* Bsl = Bs + wave * 512 + lane * 8;

    f32x4 acc[4][4];
    #pragma unroll
    for (int i = 0; i < 4; i++)
        #pragma unroll
        for (int j = 0; j < 4; j++)
            acc[i][j] = (f32x4){0.f, 0.f, 0.f, 0.f};

    for (int k0 = 0; k0 < DIMD; k0 += 64) {
        __syncthreads();
        #pragma unroll
        for (int g = 0; g < 4; g++) {
            gload16(Ag + k0 + g * 32 * DIMD, Asl + g * 2048);
            gload16(Bg + k0 + g * 32 * DIMD, Bsl + g * 2048);
        }
        __syncthreads();
        #pragma unroll
        for (int kk = 0; kk < 2; kk++) {
            bf16x8 af[4], bfr[4];
            #pragma unroll
            for (int i = 0; i < 4; i++) {
                af[i]  = *(const bf16x8*)&As[(mhalf + i * 16 + lm) * 64 + kk * 32 + quad * 8];
                bfr[i] = *(const bf16x8*)&Bs[(nhalf + i * 16 + lm) * 64 + kk * 32 + quad * 8];
            }
            #pragma unroll
            for (int i = 0; i < 4; i++)
                #pragma unroll
                for (int j = 0; j < 4; j++)
                    acc[i][j] = __builtin_amdgcn_mfma_f32_16x16x32_bf16(af[i], bfr[j], acc[i][j], 0, 0, 0);
        }
    }

    float biasj[4];
    #pragma unroll
    for (int j = 0; j < 4; j++) biasj[j] = biascat[n0 + nhalf + j * 16 + lm];

    if (BF) {
        // 2 passes, 2 i-tiles per pass. Staging stride 136 u16 (68 dwords):
        // quad-row spacing 4*68=272 dw == 16 mod 32 -> free 2-way, not 4-way.
        #pragma unroll
        for (int p = 0; p < 2; p++) {
            __syncthreads();
            #pragma unroll
            for (int ii = 0; ii < 2; ii++) {
                int i = p * 2 + ii;
                #pragma unroll
                for (int j = 0; j < 4; j++)
                    #pragma unroll
                    for (int r = 0; r < 4; r++)
                        smem[(ii * 32 + (wave >> 1) * 16 + quad * 4 + r) * 136 + nhalf + j * 16 + lm] =
                            f2bf(acc[i][j][r] + biasj[j]);
            }
            __syncthreads();
            #pragma unroll
            for (int u = 0; u < 4; u++) {
                int cch = t + u * 256;            // 0..1023
                int R = cch >> 4, ci = cch & 15;  // R 0..63
                int i = p * 2 + (R >> 5);
                int Rr = R & 31;
                long grow = m0 + (Rr >> 4) * 64 + i * 16 + (Rr & 15);
                int gcol = n0 + ci * 8;
                int4 val = *(const int4*)&smem[R * 136 + ci * 8];
                if (NSEC == 1) {
                    *(int4*)((u16*)C0v + grow * 512 + gcol) = val;
                } else if (NSEC == 2) {
                    if (gcol < 512)          *(int4*)((u16*)C0v + grow * 512 + gcol) = val;
                    else if (gcol < Nvalid)  *(int4*)((u16*)Cgv + grow * 32 + (gcol - 512)) = val;
                } else {
                    if (gcol < 512)          *(int4*)((u16*)C0v + grow * 512 + gcol) = val;
                    else if (gcol < 1024)    *(int4*)((u16*)C1v + grow * 512 + (gcol - 512)) = val;
                    else if (gcol < Nvalid)  *(int4*)((u16*)Cgv + grow * 32 + (gcol - 1024)) = val;
                }
            }
        }
    } else {
        // fp32 path: stride 132 floats (== 4 mod 8 quads-of-4 spacing -> 2-way max)
        float* Stg = (float*)smem;   // 32*132*4B = 16.9 KB <= 32 KB
        for (int i = 0; i < 4; i++) {
            __syncthreads();
            #pragma unroll
            for (int j = 0; j < 4; j++)
                #pragma unroll
                for (int r = 0; r < 4; r++)
                    Stg[((wave >> 1) * 16 + quad * 4 + r) * 132 + nhalf + j * 16 + lm] =
                        acc[i][j][r] + biasj[j];
            __syncthreads();
            #pragma unroll
            for (int u = 0; u < 4; u++) {
                int cch = t + u * 256;
                int R = cch >> 5, ci = cch & 31;
                long grow = m0 + (R >> 4) * 64 + i * 16 + (R & 15);
                int gcol = n0 + ci * 4;
                *(float4*)((float*)C0v + grow * 512 + gcol) = *(const float4*)&Stg[R * 132 + ci * 4];
            }
        }
    }
}

// ===========================================================================
// K1a: prep_w — weight-space / latency-chain work.
//   [0,64)        film_h
//   [64,192)      gatefuse
//   [192,200)     biascat
//   [200,1224)    transposes
// ===========================================================================
#define PW_FILMH   64
#define PW_GATE    (PW_FILMH + 128)    // 192
#define PW_BIAS    (PW_GATE + 8)       // 200
#define PW_TOTAL   (PW_BIAS + 1024)    // 1224

__global__ __launch_bounds__(256) void prep_w_kernel(
    const float* __restrict__ ctx0, const float* __restrict__ ctx1,
    const float* __restrict__ Wc0, const float* __restrict__ bc0,
    const float* __restrict__ Wc1, const float* __restrict__ bc1,
    float* __restrict__ h,
    const float* __restrict__ Wk, const float* __restrict__ Wv,
    const float* __restrict__ Wq, const float* __restrict__ Wo,
    u16* __restrict__ Btkv, u16* __restrict__ Btq, u16* __restrict__ Bto,
    const float* __restrict__ Wgk, const float* __restrict__ Wgq,
    const float* __restrict__ bk, const float* __restrict__ bv,
    const float* __restrict__ bq, float* __restrict__ biaskv,
    float* __restrict__ biasq)
{
    __shared__ float tile[32][33];
    int bid = blockIdx.x;
    if (bid < PW_FILMH) {
        film_h_body(bid, ctx0, ctx1, Wc0, bc0, Wc1, bc1, h);
    } else if (bid < PW_GATE) {
        int gid = bid - PW_FILMH;
        int idx = (gid & 63) * 256 + threadIdx.x;
        if (gid < 64) gatefuse_body(idx, Wk, Wgk, Btkv, 1024);
        else          gatefuse_body(idx, Wq, Wgq, Btq, 512);
    } else if (bid < PW_BIAS) {
        int cid = bid - PW_GATE;
        if (cid < 5) biascat3_body(cid, bk, bv, Wgk, biaskv);
        else         biascat2_body(cid - 5, bq, Wgq, biasq);
    } else {
        int tid = bid - PW_BIAS;
        int which = tid >> 8, i = tid & 255;
        if (which == 0)      transpose_body(i, Wk, Btkv, 0, tile);
        else if (which == 1) transpose_body(i, Wv, Btkv, 512, tile);
        else if (which == 2) transpose_body(i, Wq, Btq, 0, tile);
        else                 transpose_body(i, Wo, Bto, 0, tile);
    }
}

// ===========================================================================
// K1b: prep_s — streaming work (stats + norm0), 8 rows/wave.
// ===========================================================================
#define PS_STATS   256
#define PS_TOTAL   (PS_STATS + 1024)   // 1280

__global__ __launch_bounds__(256) void prep_s_kernel(
    const float* __restrict__ source, const float* __restrict__ kvn_g,
    const float* __restrict__ kvn_b, u16* __restrict__ sln,
    const float* __restrict__ query, float* __restrict__ mu_q, float* __restrict__ rs_q)
{
    int bid = blockIdx.x;
    int wave = threadIdx.x >> 6;
    if (bid < PS_STATS) {
        stats_body8(bid * 4 + wave, query, mu_q, rs_q);
    } else {
        norm0_body8((bid - PS_STATS) * 4 + wave, source, kvn_g, kvn_b, sln);
    }
}

// ===========================================================================
// K2: film_gb (64 blocks) + kv projection GEMM (2304 blocks)
// ===========================================================================
__global__ __launch_bounds__(256) void kv_kernel(
    const float* __restrict__ h, const float* __restrict__ Wf,
    const float* __restrict__ bfv, float* __restrict__ gamma, float* __restrict__ beta,
    const u16* __restrict__ sln, const u16* __restrict__ Btkv,
    const float* __restrict__ biaskv,
    u16* __restrict__ kp, u16* __restrict__ vp, u16* __restrict__ gk)
{
    __shared__ u16 smem[16384];
    int bid = blockIdx.x;
    if (bid < 64) {
        film_gb_body(bid, h, Wf, bfv, gamma, beta);
    } else {
        gemm_body<3, true>(bid - 64, sln, Btkv, biaskv, kp, vp, gk, 1056, 9, 32, smem);
    }
}

// ===========================================================================
// K3: q projection GEMM with LN+FiLM fused into A-staging (BK=32, unchanged)
// ===========================================================================
__global__ __launch_bounds__(256) void qproj_kernel(
    const float* __restrict__ query, const float* __restrict__ mu_q,
    const float* __restrict__ rs_q, const float* __restrict__ qn_g,
    const float* __restrict__ qn_b, const float* __restrict__ gamma,
    const float* __restrict__ beta, const u16* __restrict__ Btq,
    const float* __restrict__ biasq, u16* __restrict__ qp, u16* __restrict__ gq)
{
    __shared__ u16 smem[8192];
    u16* As = smem;
    u16* Bs = smem + 4096;

    int t = threadIdx.x;
    int wave = t >> 6, lane = t & 63;
    int id = blockIdx.x;
    int xcd = id & 7, li = id >> 3;
    int by = xcd * 8 + li / 5;
    int bx = li % 5;
    int m0 = by * 128, n0 = bx * 128;
    int mhalf = (wave >> 1) * 64, nhalf = (wave & 1) * 64;
    int lm = lane & 15, quad = lane >> 4;
    int bt = m0 >> 10;                    // batch (128 | 1024, uniform per block)

    int srow = wave * 32 + (lane >> 2);
    int scol = (lane & 3) * 8;
    const u16* Bg = Btq + (long)(n0 + srow) * DIMD + scol;
    u16* Bsl = Bs + wave * 1024 + lane * 8;

    f32x4 acc[4][4];
    #pragma unroll
    for (int i = 0; i < 4; i++)
        #pragma unroll
        for (int j = 0; j < 4; j++)
            acc[i][j] = (f32x4){0.f, 0.f, 0.f, 0.f};

    for (int k0 = 0; k0 < DIMD; k0 += 32) {
        __syncthreads();
        gload16(Bg + k0, Bsl);
        gload16(Bg + 16 * DIMD + k0, Bsl + 512);
        // A staging: LN+FiLM inline, 2 chunks of 8 elements per thread
        #pragma unroll
        for (int u = 0; u < 2; u++) {
            int idx = t + u * 256;            // 0..511
            int r = idx >> 2;                 // row 0..127
            int c8 = (idx & 3) * 8;           // col 0,8,16,24
            long grow = m0 + r;
            int col = k0 + c8;
            const float* xp = &query[grow * DIMD + col];
            float4 x0 = *(const float4*)xp, x1 = *(const float4*)(xp + 4);
            float mu = mu_q[grow], rs = rs_q[grow];
            float4 g0 = *(const float4*)&qn_g[col], g1 = *(const float4*)&qn_g[col + 4];
            float4 b0 = *(const float4*)&qn_b[col], b1 = *(const float4*)&qn_b[col + 4];
            const float* gp = gamma + bt * DIMD + col;
            const float* bp = beta + bt * DIMD + col;
            float4 gm0 = *(const float4*)gp, gm1 = *(const float4*)(gp + 4);
            float4 be0 = *(const float4*)bp, be1 = *(const float4*)(bp + 4);
            u16 o8[8];
            o8[0] = f2bf(((x0.x - mu) * rs * g0.x + b0.x) * (1.f + gm0.x) + be0.x);
            o8[1] = f2bf(((x0.y - mu) * rs * g0.y + b0.y) * (1.f + gm0.y) + be0.y);
            o8[2] = f2bf(((x0.z - mu) * rs * g0.z + b0.z) * (1.f + gm0.z) + be0.z);
            o8[3] = f2bf(((x0.w - mu) * rs * g0.w + b0.w) * (1.f + gm0.w) + be0.w);
            o8[4] = f2bf(((x1.x - mu) * rs * g1.x + b1.x) * (1.f + gm1.x) + be1.x);
            o8[5] = f2bf(((x1.y - mu) * rs * g1.y + b1.y) * (1.f + gm1.y) + be1.y);
            o8[6] = f2bf(((x1.z - mu) * rs * g1.z + b1.z) * (1.f + gm1.z) + be1.z);
            o8[7] = f2bf(((x1.w - mu) * rs * g1.w + b1.w) * (1.f + gm1.w) + be1.w);
            *(int4*)&As[r * 32 + c8] = *(const int4*)o8;
        }
        __syncthreads();
        bf16x8 af[4], bfr[4];
        #pragma unroll
        for (int i = 0; i < 4; i++) {
            af[i]  = *(const bf16x8*)&As[(mhalf + i * 16 + lm) * 32 + quad * 8];
            bfr[i] = *(const bf16x8*)&Bs[(nhalf + i * 16 + lm) * 32 + quad * 8];
        }
        #pragma unroll
        for (int i = 0; i < 4; i++)
            #pragma unroll
            for (int j = 0; j < 4; j++)
                acc[i][j] = __builtin_amdgcn_mfma_f32_16x16x32_bf16(af[i], bfr[j], acc[i][j], 0, 0, 0);
    }

    float biasj[4];
    #pragma unroll
    for (int j = 0; j < 4; j++) biasj[j] = biasq[n0 + nhalf + j * 16 + lm];

    for (int i = 0; i < 4; i++) {
        __syncthreads();
        #pragma unroll
        for (int j = 0; j < 4; j++)
            #pragma unroll
            for (int r = 0; r < 4; r++)
                smem[((wave >> 1) * 16 + quad * 4 + r) * 128 + nhalf + j * 16 + lm] =
                    f2bf(acc[i][j][r] + biasj[j]);
        __syncthreads();
        #pragma unroll
        for (int u = 0; u < 2; u++) {
            int cch = t + u * 256;
            int R = cch >> 4, ci = cch & 15;
            long grow = m0 + (R >> 4) * 64 + i * 16 + (R & 15);
            int gcol = n0 + ci * 8;
            int4 val = *(const int4*)&smem[R * 128 + ci * 8];
            if (gcol < 512)       *(int4*)(qp + grow * 512 + gcol) = val;
            else if (gcol < 544)  *(int4*)(gq + grow * 32 + (gcol - 512)) = val;
        }
    }
}

// ===========================================================================
// K5: output projection (fp32 out)
// ===========================================================================
__global__ __launch_bounds__(256) void ogemm_kernel(
    const u16* __restrict__ ctxb, const u16* __restrict__ Bto,
    const float* __restrict__ bo, float* __restrict__ out)
{
    __shared__ u16 smem[16384];
    gemm_body<1, false>(blockIdx.x, ctxb, Bto, bo, out, nullptr, nullptr, 512, 4, 8, smem);
}

// ===========================================================================
// K4: Flash-style local attention (unchanged)
// ===========================================================================
__global__ __launch_bounds__(256, 2) void attn_kernel(
    const u16* __restrict__ q_bf, const u16* __restrict__ k_bf,
    const u16* __restrict__ v_bf, const u16* __restrict__ gq_bf,
    const u16* __restrict__ gk_bf, u16* __restrict__ ctx)
{
    __shared__ u16 Ks[16 * 512];
    __shared__ u16 Vt[512 * 32];
    __shared__ u16 Pb[16 * 40];
    __shared__ float part[4][16][16];
    __shared__ float Gb[16][16];
    __shared__ float alphap[16];
    __shared__ float linv[16];

    int blk = blockIdx.x;
    int b = blk >> 6, qs = blk & 63;
    int center = (int)(qs * (255.0f / 63.0f) + 0.5f);
    int lo = center - WIN; if (lo < 0) lo = 0;
    int hi = center + WIN; if (hi > KS - 1) hi = KS - 1;
    int nst = hi - lo + 1;
    long rowq0 = (long)b * NQ + qs * 16;
    long rowk0 = (long)b * NK + lo * 16;

    int t = threadIdx.x;
    int wave = t >> 6, lane = t & 63;
    int lm = lane & 15, quad = lane >> 4;
    int qi = t >> 4, ki = t & 15;

    bf16x8 qf[4];
    #pragma unroll
    for (int f = 0; f < 4; f++)
        qf[f] = *(const bf16x8*)&q_bf[(rowq0 + lm) * DIMD + wave * 128 + f * 32 + quad * 8];
    bf16x8 gqf;
    if (wave == 3) gqf = *(const bf16x8*)&gq_bf[(rowq0 + lm) * RANK + quad * 8];

    int4 kpre[4], vpre[4];
    #pragma unroll
    for (int u = 0; u < 4; u++) {
        int idx = u * 256 + t;
        kpre[u] = *(const int4*)&k_bf[(rowk0 + (idx >> 6)) * DIMD + (idx & 63) * 8];
        int vkv = (idx >> 2) & 15, vdc = (idx & 3) | ((idx >> 6) << 2);
        vpre[u] = *(const int4*)&v_bf[(rowk0 + vkv) * DIMD + vdc * 8];
    }

    float m_run = -1e30f, l_run = 0.f;
    f32x4 acc[8];
    #pragma unroll
    for (int j = 0; j < 8; j++) acc[j] = (f32x4){0.f, 0.f, 0.f, 0.f};

    const float scale = 0.044194173824159216f;   // 512^-0.5
    const float grs = 0.17677669529663687f;      // 32^-0.5

    for (int s = 0; s < nst; s++) {
        int half = s & 1;
        #pragma unroll
        for (int u = 0; u < 4; u++) {
            int idx = u * 256 + t;
            int row = idx >> 6, c = idx & 63;
            *(int4*)&Ks[row * 512 + (c ^ (row & 7)) * 8] = kpre[u];
            int vkv = (idx >> 2) & 15, vdc = (idx & 3) | ((idx >> 6) << 2);
            int kvp = half * 16 + vkv;
            u16 vv[8];
            *(int4*)vv = vpre[u];
            #pragma unroll
            for (int i = 0; i < 8; i++) {
                int d = vdc * 8 + i;
                Vt[d * 32 + (((kvp >> 3) ^ (d & 3)) << 3) + (kvp & 7)] = vv[i];
            }
        }
        __syncthreads();
        if (s + 1 < nst) {
            long rk = rowk0 + (long)(s + 1) * 16;
            #pragma unroll
            for (int u = 0; u < 4; u++) {
                int idx = u * 256 + t;
                kpre[u] = *(const int4*)&k_bf[(rk + (idx >> 6)) * DIMD + (idx & 63) * 8];
                int vkv = (idx >> 2) & 15, vdc = (idx & 3) | ((idx >> 6) << 2);
                vpre[u] = *(const int4*)&v_bf[(rk + vkv) * DIMD + vdc * 8];
            }
        }
        f32x4 sacc = (f32x4){0.f, 0.f, 0.f, 0.f};
        #pragma unroll
        for (int f = 0; f < 4; f++) {
            int cidx = wave * 16 + f * 4 + quad;
            bf16x8 kf = *(const bf16x8*)&Ks[lm * 512 + (cidx ^ (lm & 7)) * 8];
            sacc = __builtin_amdgcn_mfma_f32_16x16x32_bf16(qf[f], kf, sacc, 0, 0, 0);
        }
        #pragma unroll
        for (int r = 0; r < 4; r++) part[wave][quad * 4 + r][lm] = sacc[r];
        if (wave == 3) {
            bf16x8 gkf = *(const bf16x8*)&gk_bf[(rowk0 + (long)s * 16 + lm) * RANK + quad * 8];
            f32x4 gacc = (f32x4){0.f, 0.f, 0.f, 0.f};
            gacc = __builtin_amdgcn_mfma_f32_16x16x32_bf16(gqf, gkf, gacc, 0, 0, 0);
            #pragma unroll
            for (int r = 0; r < 4; r++) Gb[quad * 4 + r][lm] = gacc[r];
        }
        __syncthreads();
        float sv = (part[0][qi][ki] + part[1][qi][ki] + part[2][qi][ki] + part[3][qi][ki]) * scale;
        float gl = Gb[qi][ki] * grs;
        float sig = 1.f / (1.f + expf(-gl));
        sv += logf(sig + 1e-6f);
        float mx = sv;
        mx = fmaxf(mx, __shfl_xor(mx, 1));
        mx = fmaxf(mx, __shfl_xor(mx, 2));
        mx = fmaxf(mx, __shfl_xor(mx, 4));
        mx = fmaxf(mx, __shfl_xor(mx, 8));
        float m_new = fmaxf(m_run, mx);
        float p = expf(sv - m_new);
        float ps = p;
        ps += __shfl_xor(ps, 1);
        ps += __shfl_xor(ps, 2);
        ps += __shfl_xor(ps, 4);
        ps += __shfl_xor(ps, 8);
        float alpha = expf(m_run - m_new);
        l_run = l_run * alpha + ps;
        m_run = m_new;
        Pb[qi * 40 + half * 16 + ki] = f2bf(p);
        if (half == 1) {
            Pb[qi * 40 + ki] = f2bf(bf2f(Pb[qi * 40 + ki]) * alpha);
        }
        bool dopv = (half == 1) || (s == nst - 1);
        if (dopv && half == 0) Pb[qi * 40 + 16 + ki] = 0;
        if (ki == 0) {
            if (half == 0) alphap[qi] = alpha;
            else           alphap[qi] *= alpha;
            if (s == nst - 1) linv[qi] = 1.f / l_run;
        }
        __syncthreads();
        if (dopv) {
            float ar[4];
            #pragma unroll
            for (int r = 0; r < 4; r++) ar[r] = alphap[quad * 4 + r];
            #pragma unroll
            for (int j = 0; j < 8; j++)
                #pragma unroll
                for (int r = 0; r < 4; r++) acc[j][r] *= ar[r];
            bf16x8 pf = *(const bf16x8*)&Pb[lm * 40 + quad * 8];
            #pragma unroll
            for (int j = 0; j < 8; j++) {
                int d = wave * 128 + j * 16 + lm;
                bf16x8 vf = *(const bf16x8*)&Vt[d * 32 + ((quad ^ (d & 3)) << 3)];
                acc[j] = __builtin_amdgcn_mfma_f32_16x16x32_bf16(pf, vf, acc[j], 0, 0, 0);
            }
            __syncthreads();
        }
    }
    float li[4];
    #pragma unroll
    for (int r = 0; r < 4; r++) li[r] = linv[quad * 4 + r];
    #pragma unroll
    for (int j = 0; j < 8; j++) {
        int d = wave * 128 + j * 16 + lm;
        #pragma unroll
        for (int r = 0; r < 4; r++)
            ctx[(rowq0 + quad * 4 + r) * DIMD + d] = f2bf(acc[j][r] * li[r]);
    }
}

// ---------------------------------------------------------------------------
extern "C" void kernel_launch(void* const* d_in, const int* in_sizes, int n_in,
                              void* d_out, int out_size, void* d_ws, size_t ws_size,
                              hipStream_t stream) {
    const float* query  = (const float*)d_in[0];
    const float* source = (const float*)d_in[1];
    const float* ctx0   = (const float*)d_in[2];
    const float* ctx1   = (const float*)d_in[3];
    // d_in[4] = mask: structurally known local window, unused
    const float* qn_g  = (const float*)d_in[5];
    const float* qn_b  = (const float*)d_in[6];
    const float* kvn_g = (const float*)d_in[7];
    const float* kvn_b = (const float*)d_in[8];
    const float* Wq = (const float*)d_in[9];   const float* bq = (const float*)d_in[10];
    const float* Wk = (const float*)d_in[11];  const float* bk = (const float*)d_in[12];
    const float* Wv = (const float*)d_in[13];  const float* bv = (const float*)d_in[14];
    const float* Wo = (const float*)d_in[15];  const float* bo = (const float*)d_in[16];
    const float* Wgq = (const float*)d_in[17];
    const float* Wgk = (const float*)d_in[18];
    const float* Wc0 = (const float*)d_in[19]; const float* bc0 = (const float*)d_in[20];
    const float* Wc1 = (const float*)d_in[21]; const float* bc1 = (const float*)d_in[22];
    const float* Wf  = (const float*)d_in[23]; const float* bfv = (const float*)d_in[24];

    // ---- workspace layout ----
    float* ws = (float*)d_ws;
    float* h      = ws;                         // 4096
    float* gamma  = h + 4096;                   // 4096
    float* beta   = gamma + 4096;               // 4096
    float* biaskv = beta + 4096;                // 1152
    float* biasq  = biaskv + 1152;              // 640
    float* mu_q   = biasq + 640;                // 8192
    float* rs_q   = mu_q + 8192;                // 8192
    u16* u = (u16*)(rs_q + 8192);
    u16* sln  = u;                 u += (long)MK * DIMD;   // LN(source) bf16
    u16* kp   = u;                 u += (long)MK * DIMD;   // k proj bf16
    u16* vp   = u;                 u += (long)MK * DIMD;   // v proj bf16
    u16* gk   = u;                 u += (long)MK * RANK;   // gate_k bf16
    u16* gq   = u;                 u += (long)MQ * RANK;   // gate_q bf16
    u16* qp   = u;                 u += (long)MQ * DIMD;   // q proj bf16
    u16* ctxb = u;                 u += (long)MQ * DIMD;   // attention output bf16
    u16* Btkv = u;                 u += 1152L * DIMD;      // [Wk^T | Wv^T | (Wk·Wgk)^T]
    u16* Btq  = u;                 u += 640L * DIMD;       // [Wq^T | (Wq·Wgq)^T]
    u16* Bto  = u;                 u += 512L * DIMD;       // Wo^T
    float* out = (float*)d_out;

    // K1a: weight-space prep (latency chains)
    prep_w_kernel<<<PW_TOTAL, 256, 0, stream>>>(
        ctx0, ctx1, Wc0, bc0, Wc1, bc1, h,
        Wk, Wv, Wq, Wo, Btkv, Btq, Bto,
        Wgk, Wgq, bk, bv, bq, biaskv, biasq);

    // K1b: streaming prep (stats + norm0)
    prep_s_kernel<<<PS_TOTAL, 256, 0, stream>>>(
        source, kvn_g, kvn_b, sln, query, mu_q, rs_q);

    // K2: film_gb + kv projection GEMM
    kv_kernel<<<64 + 2304, 256, 0, stream>>>(
        h, Wf, bfv, gamma, beta, sln, Btkv, biaskv, kp, vp, gk);

    // K3: q projection GEMM (LN+FiLM inline)
    qproj_kernel<<<320, 256, 0, stream>>>(
        query, mu_q, rs_q, qn_g, qn_b, gamma, beta, Btq, biasq, qp, gq);

    // K4: flash local attention
    attn_kernel<<<BATCH * QS, 256, 0, stream>>>(qp, kp, vp, gq, gk, ctxb);

    // K5: output projection (fp32 out)
    ogemm_kernel<<<256, 256, 0, stream>>>(ctxb, Bto, bo, out);
}

// Round 4
// 357.623 us; speedup vs baseline: 1.0532x; 1.0317x over previous
//
#include <hip/hip_runtime.h>
#include <math.h>

// Problem constants
#define DIMD 512
#define QS 64
#define KS 256
#define WIN 4
#define BATCH 8
#define RANK 32
#define NQ 1024             // q tokens per batch
#define NK 4096             // kv tokens per batch
#define MQ (BATCH*NQ)       // 8192 q rows
#define MK (BATCH*NK)       // 32768 kv rows

typedef unsigned short u16;
typedef __attribute__((ext_vector_type(8))) short bf16x8;  // MFMA A/B frag (8 bf16)
typedef __attribute__((ext_vector_type(4))) float f32x4;   // MFMA C/D frag

__device__ inline u16 f2bf(float x) {
    union { float f; unsigned int u; } v; v.f = x;
    unsigned int r = v.u + 0x7FFF + ((v.u >> 16) & 1);
    return (u16)(r >> 16);
}
__device__ inline float bf2f(u16 x) {
    union { unsigned int u; float f; } v; v.u = ((unsigned int)x) << 16;
    return v.f;
}

// async global->LDS, 16 B per lane. LDS dest = wave-uniform base + lane*16.
__device__ __forceinline__ void gload16(const u16* g, u16* l) {
    __builtin_amdgcn_global_load_lds(
        (const __attribute__((address_space(1))) void*)g,
        (__attribute__((address_space(3))) void*)l, 16, 0, 0);
}

// ===========================================================================
// Device bodies
// ===========================================================================

// norm: LN(source)*g+b -> bf16. One wave handles 8 rows, loads issued upfront.
__device__ __forceinline__ void norm0_body8(
    int widx, const float* __restrict__ X, const float* __restrict__ g,
    const float* __restrict__ bb, u16* __restrict__ out)
{
    int lane = threadIdx.x & 63;
    long row0 = (long)widx * 8;
    int c = lane * 8;
    float4 a[8], b[8];
    #pragma unroll
    for (int i = 0; i < 8; i++) {
        const float* x = X + (row0 + i) * DIMD + c;
        a[i] = *(const float4*)x;
        b[i] = *(const float4*)(x + 4);
    }
    float s[8], ss[8];
    #pragma unroll
    for (int i = 0; i < 8; i++) {
        s[i]  = a[i].x + a[i].y + a[i].z + a[i].w + b[i].x + b[i].y + b[i].z + b[i].w;
        ss[i] = a[i].x*a[i].x + a[i].y*a[i].y + a[i].z*a[i].z + a[i].w*a[i].w
              + b[i].x*b[i].x + b[i].y*b[i].y + b[i].z*b[i].z + b[i].w*b[i].w;
    }
    #pragma unroll
    for (int o = 1; o < 64; o <<= 1) {
        #pragma unroll
        for (int i = 0; i < 8; i++) {
            s[i]  += __shfl_xor(s[i], o);
            ss[i] += __shfl_xor(ss[i], o);
        }
    }
    float4 g0 = *(const float4*)&g[c],  g1 = *(const float4*)&g[c + 4];
    float4 b0 = *(const float4*)&bb[c], b1 = *(const float4*)&bb[c + 4];
    #pragma unroll
    for (int i = 0; i < 8; i++) {
        float mu = s[i] * (1.f / DIMD);
        float var = ss[i] * (1.f / DIMD) - mu * mu;
        float rs = rsqrtf(var + 1e-5f);
        u16 o8[8];
        o8[0] = f2bf((a[i].x - mu) * rs * g0.x + b0.x);
        o8[1] = f2bf((a[i].y - mu) * rs * g0.y + b0.y);
        o8[2] = f2bf((a[i].z - mu) * rs * g0.z + b0.z);
        o8[3] = f2bf((a[i].w - mu) * rs * g0.w + b0.w);
        o8[4] = f2bf((b[i].x - mu) * rs * g1.x + b1.x);
        o8[5] = f2bf((b[i].y - mu) * rs * g1.y + b1.y);
        o8[6] = f2bf((b[i].z - mu) * rs * g1.z + b1.z);
        o8[7] = f2bf((b[i].w - mu) * rs * g1.w + b1.w);
        *(int4*)&out[(row0 + i) * DIMD + c] = *(const int4*)o8;
    }
}

// row stats for query rows: mu, rstd. One wave handles 8 rows, upfront loads.
__device__ __forceinline__ void stats_body8(
    int widx, const float* __restrict__ X, float* __restrict__ mu_o, float* __restrict__ rs_o)
{
    int lane = threadIdx.x & 63;
    long row0 = (long)widx * 8;
    int c = lane * 8;
    float4 a[8], b[8];
    #pragma unroll
    for (int i = 0; i < 8; i++) {
        const float* x = X + (row0 + i) * DIMD + c;
        a[i] = *(const float4*)x;
        b[i] = *(const float4*)(x + 4);
    }
    float s[8], ss[8];
    #pragma unroll
    for (int i = 0; i < 8; i++) {
        s[i]  = a[i].x + a[i].y + a[i].z + a[i].w + b[i].x + b[i].y + b[i].z + b[i].w;
        ss[i] = a[i].x*a[i].x + a[i].y*a[i].y + a[i].z*a[i].z + a[i].w*a[i].w
              + b[i].x*b[i].x + b[i].y*b[i].y + b[i].z*b[i].z + b[i].w*b[i].w;
    }
    #pragma unroll
    for (int o = 1; o < 64; o <<= 1) {
        #pragma unroll
        for (int i = 0; i < 8; i++) {
            s[i]  += __shfl_xor(s[i], o);
            ss[i] += __shfl_xor(ss[i], o);
        }
    }
    if (lane < 8) {
        int i = lane;
        float mu = s[i] * (1.f / DIMD);
        float var = ss[i] * (1.f / DIMD) - mu * mu;
        mu_o[row0 + i] = mu;
        rs_o[row0 + i] = rsqrtf(var + 1e-5f);
    }
}

// film_h: h = silu(ctx0@Wc0 + bc0 + ctx1@Wc1 + bc1), bid in [0,64)
__device__ __forceinline__ void film_h_body(
    int bid, const float* __restrict__ ctx0, const float* __restrict__ ctx1,
    const float* __restrict__ Wc0, const float* __restrict__ bc0,
    const float* __restrict__ Wc1, const float* __restrict__ bc1,
    float* __restrict__ h)
{
    int b = bid >> 3;
    int d0 = (bid & 7) * 64;
    int t = threadIdx.x;
    int dl = t >> 2, p = t & 3;
    int d = d0 + dl;
    const float* c0 = ctx0 + b * DIMD;
    const float* c1 = ctx1 + b * DIMD;
    float acc = 0.f;
    #pragma unroll 4
    for (int ii = 0; ii < 128; ii++) {
        int i = p * 128 + ii;
        acc = fmaf(c0[i], Wc0[i * DIMD + d], acc);
        acc = fmaf(c1[i], Wc1[i * DIMD + d], acc);
    }
    acc += __shfl_xor(acc, 1);
    acc += __shfl_xor(acc, 2);
    if (p == 0) {
        float v = acc + bc0[d] + bc1[d];
        h[b * DIMD + d] = v / (1.f + expf(-v));
    }
}

// film_gb: gamma,beta = split(h @ Wf + bf), bid in [0,64)
__device__ __forceinline__ void film_gb_body(
    int bid, const float* __restrict__ h, const float* __restrict__ Wf,
    const float* __restrict__ bfv, float* __restrict__ gamma, float* __restrict__ beta)
{
    int b = bid >> 3;
    int d0 = (bid & 7) * 64;
    int t = threadIdx.x;
    int dl = t >> 2, p = t & 3;
    int d = d0 + dl;
    const float* hb = h + b * DIMD;
    float ga = 0.f, be = 0.f;
    #pragma unroll 4
    for (int ii = 0; ii < 128; ii++) {
        int i = p * 128 + ii;
        float hv = hb[i];
        ga = fmaf(hv, Wf[i * 2 * DIMD + d], ga);
        be = fmaf(hv, Wf[i * 2 * DIMD + DIMD + d], be);
    }
    ga += __shfl_xor(ga, 1); ga += __shfl_xor(ga, 2);
    be += __shfl_xor(be, 1); be += __shfl_xor(be, 2);
    if (p == 0) {
        gamma[b * DIMD + d] = ga + bfv[d];
        beta[b * DIMD + d]  = be + bfv[DIMD + d];
    }
}

// transpose W[512][512] -> bf16 dst[dst_row_off + n][k], i in [0,256)
__device__ __forceinline__ void transpose_body(
    int i, const float* __restrict__ src, u16* __restrict__ dst, int dst_row_off,
    float (*tile)[33])
{
    int t = threadIdx.x;
    int tx = t & 31, ty = t >> 5;
    int bx = (i & 15) * 32;
    int by = (i >> 4) * 32;
    #pragma unroll
    for (int k = 0; k < 4; k++)
        tile[ty + k * 8][tx] = src[(long)(by + ty + k * 8) * DIMD + bx + tx];
    __syncthreads();
    #pragma unroll
    for (int k = 0; k < 4; k++)
        dst[(long)(dst_row_off + bx + ty + k * 8) * DIMD + by + tx] = f2bf(tile[tx][ty + k * 8]);
}

// gatefuse: dst[off+r][k] = sum_j W[k][j]*Wg[j][r], idx = global elem id
__device__ __forceinline__ void gatefuse_body(
    int idx, const float* __restrict__ W, const float* __restrict__ Wg,
    u16* __restrict__ dst, int dst_row_off)
{
    int r = idx & 31, k = idx >> 5;
    float acc = 0.f;
    #pragma unroll 4
    for (int j = 0; j < DIMD; j++) acc = fmaf(W[k * DIMD + j], Wg[j * RANK + r], acc);
    dst[(long)(dst_row_off + r) * DIMD + k] = f2bf(acc);
}

__device__ __forceinline__ void biascat3_body(
    int bid, const float* __restrict__ b0, const float* __restrict__ b1,
    const float* __restrict__ Wg, float* __restrict__ dst)
{
    int t = bid * 256 + threadIdx.x;
    if (t < 512) dst[t] = b0[t];
    else if (t < 1024) dst[t] = b1[t - 512];
    else if (t < 1056) {
        int r = t - 1024;
        float a = 0.f;
        #pragma unroll 4
        for (int j = 0; j < DIMD; j++) a = fmaf(b0[j], Wg[j * RANK + r], a);
        dst[t] = a;
    }
}

__device__ __forceinline__ void biascat2_body(
    int bid, const float* __restrict__ b0, const float* __restrict__ Wg,
    float* __restrict__ dst)
{
    int t = bid * 256 + threadIdx.x;
    if (t < 512) dst[t] = b0[t];
    else if (t < 544) {
        int r = t - 512;
        float a = 0.f;
        #pragma unroll 4
        for (int j = 0; j < DIMD; j++) a = fmaf(b0[j], Wg[j * RANK + r], a);
        dst[t] = a;
    }
}

// ---------------------------------------------------------------------------
// bf16 MFMA GEMM body, BK=64, XOR-swizzled LDS (both-sides: pre-swizzled
// global source col + swizzled ds_read chunk) -> conflict-free fragment reads.
// smem must be 16384 u16 (32 KB).
// ---------------------------------------------------------------------------
template<int NSEC, bool BF>
__device__ __forceinline__ void gemm_body(
    int id, const u16* __restrict__ A, const u16* __restrict__ Bt,
    const float* __restrict__ biascat,
    void* __restrict__ C0v, void* __restrict__ C1v, void* __restrict__ Cgv,
    int Nvalid, int nx, int ypg, u16* smem)
{
    u16* As = smem;           // [128][64] bf16, chunk-swizzled
    u16* Bs = smem + 8192;    // [128][64] bf16, chunk-swizzled

    int t = threadIdx.x;
    int wave = t >> 6, lane = t & 63;
    int xcd = id & 7, li = id >> 3;
    int by = xcd * ypg + li / nx;
    int bx = li % nx;
    int m0 = by * 128, n0 = bx * 128;
    int mhalf = (wave >> 1) * 64, nhalf = (wave & 1) * 64;
    int lm = lane & 15, quad = lane >> 4;

    // staging: per gload g, wave w covers rows g*32 + w*8 + (lane>>3).
    // LDS dest is linear (gload_lds requirement); the SOURCE column is
    // pre-swizzled so that physical chunk p=(lane&7) of row r holds logical
    // chunk p ^ (r&7)  (r&7 == lane>>3 here).
    int srow = wave * 8 + (lane >> 3);
    int scol = ((lane & 7) ^ (lane >> 3)) * 8;
    const u16* Ag = A + (long)(m0 + srow) * DIMD + scol;
    const u16* Bg = Bt + (long)(n0 + srow) * DIMD + scol;
    u16* Asl = As + wave * 512 + lane * 8;
    u16* Bsl = Bs + wave * 512 + lane * 8;

    f32x4 acc[4][4];
    #pragma unroll
    for (int i = 0; i < 4; i++)
        #pragma unroll
        for (int j = 0; j < 4; j++)
            acc[i][j] = (f32x4){0.f, 0.f, 0.f, 0.f};

    for (int k0 = 0; k0 < DIMD; k0 += 64) {
        __syncthreads();
        #pragma unroll
        for (int g = 0; g < 4; g++) {
            gload16(Ag + k0 + g * 32 * DIMD, Asl + g * 2048);
            gload16(Bg + k0 + g * 32 * DIMD, Bsl + g * 2048);
        }
        __syncthreads();
        #pragma unroll
        for (int kk = 0; kk < 2; kk++) {
            bf16x8 af[4], bfr[4];
            #pragma unroll
            for (int i = 0; i < 4; i++) {
                // logical chunk kk*4+quad of row R lives at physical chunk
                // (kk*4+quad) ^ (R&7); R&7 == lm&7 (mhalf, i*16 are 0 mod 8).
                int pc = ((kk * 4 + quad) ^ (lm & 7)) << 3;
                af[i]  = *(const bf16x8*)&As[(mhalf + i * 16 + lm) * 64 + pc];
                bfr[i] = *(const bf16x8*)&Bs[(nhalf + i * 16 + lm) * 64 + pc];
            }
            #pragma unroll
            for (int i = 0; i < 4; i++)
                #pragma unroll
                for (int j = 0; j < 4; j++)
                    acc[i][j] = __builtin_amdgcn_mfma_f32_16x16x32_bf16(af[i], bfr[j], acc[i][j], 0, 0, 0);
        }
    }

    float biasj[4];
    #pragma unroll
    for (int j = 0; j < 4; j++) biasj[j] = biascat[n0 + nhalf + j * 16 + lm];

    if (BF) {
        // 2 passes, 2 i-tiles per pass, staging stride 136 u16 (pad).
        #pragma unroll
        for (int p = 0; p < 2; p++) {
            __syncthreads();
            #pragma unroll
            for (int ii = 0; ii < 2; ii++) {
                int i = p * 2 + ii;
                #pragma unroll
                for (int j = 0; j < 4; j++)
                    #pragma unroll
                    for (int r = 0; r < 4; r++)
                        smem[(ii * 32 + (wave >> 1) * 16 + quad * 4 + r) * 136 + nhalf + j * 16 + lm] =
                            f2bf(acc[i][j][r] + biasj[j]);
            }
            __syncthreads();
            #pragma unroll
            for (int u = 0; u < 4; u++) {
                int cch = t + u * 256;            // 0..1023
                int R = cch >> 4, ci = cch & 15;  // R 0..63
                int i = p * 2 + (R >> 5);
                int Rr = R & 31;
                long grow = m0 + (Rr >> 4) * 64 + i * 16 + (Rr & 15);
                int gcol = n0 + ci * 8;
                int4 val = *(const int4*)&smem[R * 136 + ci * 8];
                if (NSEC == 1) {
                    *(int4*)((u16*)C0v + grow * 512 + gcol) = val;
                } else if (NSEC == 2) {
                    if (gcol < 512)          *(int4*)((u16*)C0v + grow * 512 + gcol) = val;
                    else if (gcol < Nvalid)  *(int4*)((u16*)Cgv + grow * 32 + (gcol - 512)) = val;
                } else {
                    if (gcol < 512)          *(int4*)((u16*)C0v + grow * 512 + gcol) = val;
                    else if (gcol < 1024)    *(int4*)((u16*)C1v + grow * 512 + (gcol - 512)) = val;
                    else if (gcol < Nvalid)  *(int4*)((u16*)Cgv + grow * 32 + (gcol - 1024)) = val;
                }
            }
        }
    } else {
        // fp32 path: stride 132 floats
        float* Stg = (float*)smem;   // 32*132*4B = 16.9 KB <= 32 KB
        for (int i = 0; i < 4; i++) {
            __syncthreads();
            #pragma unroll
            for (int j = 0; j < 4; j++)
                #pragma unroll
                for (int r = 0; r < 4; r++)
                    Stg[((wave >> 1) * 16 + quad * 4 + r) * 132 + nhalf + j * 16 + lm] =
                        acc[i][j][r] + biasj[j];
            __syncthreads();
            #pragma unroll
            for (int u = 0; u < 4; u++) {
                int cch = t + u * 256;
                int R = cch >> 5, ci = cch & 31;
                long grow = m0 + (R >> 4) * 64 + i * 16 + (R & 15);
                int gcol = n0 + ci * 4;
                *(float4*)((float*)C0v + grow * 512 + gcol) = *(const float4*)&Stg[R * 132 + ci * 4];
            }
        }
    }
}

// ===========================================================================
// K1: fused prep — latency-chain bodies first, streaming last.
//   [0,64)        film_h
//   [64,192)      gatefuse
//   [192,200)     biascat
//   [200,1224)    transposes
//   [1224,1480)   q stats   (8 rows/wave)
//   [1480,2504)   norm0     (8 rows/wave)
// ===========================================================================
#define PREP_FILMH   64
#define PREP_GATE    (PREP_FILMH + 128)    // 192
#define PREP_BIAS    (PREP_GATE + 8)       // 200
#define PREP_TRANS   (PREP_BIAS + 1024)    // 1224
#define PREP_STATS   (PREP_TRANS + 256)    // 1480
#define PREP_TOTAL   (PREP_STATS + 1024)   // 2504

__global__ __launch_bounds__(256) void prep_kernel(
    const float* __restrict__ source, const float* __restrict__ kvn_g,
    const float* __restrict__ kvn_b, u16* __restrict__ sln,
    const float* __restrict__ query, float* __restrict__ mu_q, float* __restrict__ rs_q,
    const float* __restrict__ ctx0, const float* __restrict__ ctx1,
    const float* __restrict__ Wc0, const float* __restrict__ bc0,
    const float* __restrict__ Wc1, const float* __restrict__ bc1,
    float* __restrict__ h,
    const float* __restrict__ Wk, const float* __restrict__ Wv,
    const float* __restrict__ Wq, const float* __restrict__ Wo,
    u16* __restrict__ Btkv, u16* __restrict__ Btq, u16* __restrict__ Bto,
    const float* __restrict__ Wgk, const float* __restrict__ Wgq,
    const float* __restrict__ bk, const float* __restrict__ bv,
    const float* __restrict__ bq, float* __restrict__ biaskv,
    float* __restrict__ biasq)
{
    __shared__ float tile[32][33];
    int bid = blockIdx.x;
    int wave = threadIdx.x >> 6;
    if (bid < PREP_FILMH) {
        film_h_body(bid, ctx0, ctx1, Wc0, bc0, Wc1, bc1, h);
    } else if (bid < PREP_GATE) {
        int gid = bid - PREP_FILMH;
        int idx = (gid & 63) * 256 + threadIdx.x;
        if (gid < 64) gatefuse_body(idx, Wk, Wgk, Btkv, 1024);
        else          gatefuse_body(idx, Wq, Wgq, Btq, 512);
    } else if (bid < PREP_BIAS) {
        int cid = bid - PREP_GATE;
        if (cid < 5) biascat3_body(cid, bk, bv, Wgk, biaskv);
        else         biascat2_body(cid - 5, bq, Wgq, biasq);
    } else if (bid < PREP_TRANS) {
        int tid = bid - PREP_BIAS;
        int which = tid >> 8, i = tid & 255;
        if (which == 0)      transpose_body(i, Wk, Btkv, 0, tile);
        else if (which == 1) transpose_body(i, Wv, Btkv, 512, tile);
        else if (which == 2) transpose_body(i, Wq, Btq, 0, tile);
        else                 transpose_body(i, Wo, Bto, 0, tile);
    } else if (bid < PREP_STATS) {
        stats_body8((bid - PREP_TRANS) * 4 + wave, query, mu_q, rs_q);
    } else {
        norm0_body8((bid - PREP_STATS) * 4 + wave, source, kvn_g, kvn_b, sln);
    }
}

// ===========================================================================
// K2: film_gb (64 blocks) + kv projection GEMM (2304 blocks)
// ===========================================================================
__global__ __launch_bounds__(256) void kv_kernel(
    const float* __restrict__ h, const float* __restrict__ Wf,
    const float* __restrict__ bfv, float* __restrict__ gamma, float* __restrict__ beta,
    const u16* __restrict__ sln, const u16* __restrict__ Btkv,
    const float* __restrict__ biaskv,
    u16* __restrict__ kp, u16* __restrict__ vp, u16* __restrict__ gk)
{
    __shared__ u16 smem[16384];
    int bid = blockIdx.x;
    if (bid < 64) {
        film_gb_body(bid, h, Wf, bfv, gamma, beta);
    } else {
        gemm_body<3, true>(bid - 64, sln, Btkv, biaskv, kp, vp, gk, 1056, 9, 32, smem);
    }
}

// ===========================================================================
// K3: q projection GEMM with LN+FiLM fused into A-staging (BK=32, unchanged)
// ===========================================================================
__global__ __launch_bounds__(256) void qproj_kernel(
    const float* __restrict__ query, const float* __restrict__ mu_q,
    const float* __restrict__ rs_q, const float* __restrict__ qn_g,
    const float* __restrict__ qn_b, const float* __restrict__ gamma,
    const float* __restrict__ beta, const u16* __restrict__ Btq,
    const float* __restrict__ biasq, u16* __restrict__ qp, u16* __restrict__ gq)
{
    __shared__ u16 smem[8192];
    u16* As = smem;
    u16* Bs = smem + 4096;

    int t = threadIdx.x;
    int wave = t >> 6, lane = t & 63;
    int id = blockIdx.x;
    int xcd = id & 7, li = id >> 3;
    int by = xcd * 8 + li / 5;
    int bx = li % 5;
    int m0 = by * 128, n0 = bx * 128;
    int mhalf = (wave >> 1) * 64, nhalf = (wave & 1) * 64;
    int lm = lane & 15, quad = lane >> 4;
    int bt = m0 >> 10;                    // batch (128 | 1024, uniform per block)

    int srow = wave * 32 + (lane >> 2);
    int scol = (lane & 3) * 8;
    const u16* Bg = Btq + (long)(n0 + srow) * DIMD + scol;
    u16* Bsl = Bs + wave * 1024 + lane * 8;

    f32x4 acc[4][4];
    #pragma unroll
    for (int i = 0; i < 4; i++)
        #pragma unroll
        for (int j = 0; j < 4; j++)
            acc[i][j] = (f32x4){0.f, 0.f, 0.f, 0.f};

    for (int k0 = 0; k0 < DIMD; k0 += 32) {
        __syncthreads();
        gload16(Bg + k0, Bsl);
        gload16(Bg + 16 * DIMD + k0, Bsl + 512);
        // A staging: LN+FiLM inline, 2 chunks of 8 elements per thread
        #pragma unroll
        for (int u = 0; u < 2; u++) {
            int idx = t + u * 256;            // 0..511
            int r = idx >> 2;                 // row 0..127
            int c8 = (idx & 3) * 8;           // col 0,8,16,24
            long grow = m0 + r;
            int col = k0 + c8;
            const float* xp = &query[grow * DIMD + col];
            float4 x0 = *(const float4*)xp, x1 = *(const float4*)(xp + 4);
            float mu = mu_q[grow], rs = rs_q[grow];
            float4 g0 = *(const float4*)&qn_g[col], g1 = *(const float4*)&qn_g[col + 4];
            float4 b0 = *(const float4*)&qn_b[col], b1 = *(const float4*)&qn_b[col + 4];
            const float* gp = gamma + bt * DIMD + col;
            const float* bp = beta + bt * DIMD + col;
            float4 gm0 = *(const float4*)gp, gm1 = *(const float4*)(gp + 4);
            float4 be0 = *(const float4*)bp, be1 = *(const float4*)(bp + 4);
            u16 o8[8];
            o8[0] = f2bf(((x0.x - mu) * rs * g0.x + b0.x) * (1.f + gm0.x) + be0.x);
            o8[1] = f2bf(((x0.y - mu) * rs * g0.y + b0.y) * (1.f + gm0.y) + be0.y);
            o8[2] = f2bf(((x0.z - mu) * rs * g0.z + b0.z) * (1.f + gm0.z) + be0.z);
            o8[3] = f2bf(((x0.w - mu) * rs * g0.w + b0.w) * (1.f + gm0.w) + be0.w);
            o8[4] = f2bf(((x1.x - mu) * rs * g1.x + b1.x) * (1.f + gm1.x) + be1.x);
            o8[5] = f2bf(((x1.y - mu) * rs * g1.y + b1.y) * (1.f + gm1.y) + be1.y);
            o8[6] = f2bf(((x1.z - mu) * rs * g1.z + b1.z) * (1.f + gm1.z) + be1.z);
            o8[7] = f2bf(((x1.w - mu) * rs * g1.w + b1.w) * (1.f + gm1.w) + be1.w);
            *(int4*)&As[r * 32 + c8] = *(const int4*)o8;
        }
        __syncthreads();
        bf16x8 af[4], bfr[4];
        #pragma unroll
        for (int i = 0; i < 4; i++) {
            af[i]  = *(const bf16x8*)&As[(mhalf + i * 16 + lm) * 32 + quad * 8];
            bfr[i] = *(const bf16x8*)&Bs[(nhalf + i * 16 + lm) * 32 + quad * 8];
        }
        #pragma unroll
        for (int i = 0; i < 4; i++)
            #pragma unroll
            for (int j = 0; j < 4; j++)
                acc[i][j] = __builtin_amdgcn_mfma_f32_16x16x32_bf16(af[i], bfr[j], acc[i][j], 0, 0, 0);
    }

    float biasj[4];
    #pragma unroll
    for (int j = 0; j < 4; j++) biasj[j] = biasq[n0 + nhalf + j * 16 + lm];

    for (int i = 0; i < 4; i++) {
        __syncthreads();
        #pragma unroll
        for (int j = 0; j < 4; j++)
            #pragma unroll
            for (int r = 0; r < 4; r++)
                smem[((wave >> 1) * 16 + quad * 4 + r) * 128 + nhalf + j * 16 + lm] =
                    f2bf(acc[i][j][r] + biasj[j]);
        __syncthreads();
        #pragma unroll
        for (int u = 0; u < 2; u++) {
            int cch = t + u * 256;
            int R = cch >> 4, ci = cch & 15;
            long grow = m0 + (R >> 4) * 64 + i * 16 + (R & 15);
            int gcol = n0 + ci * 8;
            int4 val = *(const int4*)&smem[R * 128 + ci * 8];
            if (gcol < 512)       *(int4*)(qp + grow * 512 + gcol) = val;
            else if (gcol < 544)  *(int4*)(gq + grow * 32 + (gcol - 512)) = val;
        }
    }
}

// ===========================================================================
// K5: output projection (fp32 out)
// ===========================================================================
__global__ __launch_bounds__(256) void ogemm_kernel(
    const u16* __restrict__ ctxb, const u16* __restrict__ Bto,
    const float* __restrict__ bo, float* __restrict__ out)
{
    __shared__ u16 smem[16384];
    gemm_body<1, false>(blockIdx.x, ctxb, Bto, bo, out, nullptr, nullptr, 512, 4, 8, smem);
}

// ===========================================================================
// K4: Flash-style local attention (unchanged)
// ===========================================================================
__global__ __launch_bounds__(256, 2) void attn_kernel(
    const u16* __restrict__ q_bf, const u16* __restrict__ k_bf,
    const u16* __restrict__ v_bf, const u16* __restrict__ gq_bf,
    const u16* __restrict__ gk_bf, u16* __restrict__ ctx)
{
    __shared__ u16 Ks[16 * 512];
    __shared__ u16 Vt[512 * 32];
    __shared__ u16 Pb[16 * 40];
    __shared__ float part[4][16][16];
    __shared__ float Gb[16][16];
    __shared__ float alphap[16];
    __shared__ float linv[16];

    int blk = blockIdx.x;
    int b = blk >> 6, qs = blk & 63;
    int center = (int)(qs * (255.0f / 63.0f) + 0.5f);
    int lo = center - WIN; if (lo < 0) lo = 0;
    int hi = center + WIN; if (hi > KS - 1) hi = KS - 1;
    int nst = hi - lo + 1;
    long rowq0 = (long)b * NQ + qs * 16;
    long rowk0 = (long)b * NK + lo * 16;

    int t = threadIdx.x;
    int wave = t >> 6, lane = t & 63;
    int lm = lane & 15, quad = lane >> 4;
    int qi = t >> 4, ki = t & 15;

    bf16x8 qf[4];
    #pragma unroll
    for (int f = 0; f < 4; f++)
        qf[f] = *(const bf16x8*)&q_bf[(rowq0 + lm) * DIMD + wave * 128 + f * 32 + quad * 8];
    bf16x8 gqf;
    if (wave == 3) gqf = *(const bf16x8*)&gq_bf[(rowq0 + lm) * RANK + quad * 8];

    int4 kpre[4], vpre[4];
    #pragma unroll
    for (int u = 0; u < 4; u++) {
        int idx = u * 256 + t;
        kpre[u] = *(const int4*)&k_bf[(rowk0 + (idx >> 6)) * DIMD + (idx & 63) * 8];
        int vkv = (idx >> 2) & 15, vdc = (idx & 3) | ((idx >> 6) << 2);
        vpre[u] = *(const int4*)&v_bf[(rowk0 + vkv) * DIMD + vdc * 8];
    }

    float m_run = -1e30f, l_run = 0.f;
    f32x4 acc[8];
    #pragma unroll
    for (int j = 0; j < 8; j++) acc[j] = (f32x4){0.f, 0.f, 0.f, 0.f};

    const float scale = 0.044194173824159216f;   // 512^-0.5
    const float grs = 0.17677669529663687f;      // 32^-0.5

    for (int s = 0; s < nst; s++) {
        int half = s & 1;
        #pragma unroll
        for (int u = 0; u < 4; u++) {
            int idx = u * 256 + t;
            int row = idx >> 6, c = idx & 63;
            *(int4*)&Ks[row * 512 + (c ^ (row & 7)) * 8] = kpre[u];
            int vkv = (idx >> 2) & 15, vdc = (idx & 3) | ((idx >> 6) << 2);
            int kvp = half * 16 + vkv;
            u16 vv[8];
            *(int4*)vv = vpre[u];
            #pragma unroll
            for (int i = 0; i < 8; i++) {
                int d = vdc * 8 + i;
                Vt[d * 32 + (((kvp >> 3) ^ (d & 3)) << 3) + (kvp & 7)] = vv[i];
            }
        }
        __syncthreads();
        if (s + 1 < nst) {
            long rk = rowk0 + (long)(s + 1) * 16;
            #pragma unroll
            for (int u = 0; u < 4; u++) {
                int idx = u * 256 + t;
                kpre[u] = *(const int4*)&k_bf[(rk + (idx >> 6)) * DIMD + (idx & 63) * 8];
                int vkv = (idx >> 2) & 15, vdc = (idx & 3) | ((idx >> 6) << 2);
                vpre[u] = *(const int4*)&v_bf[(rk + vkv) * DIMD + vdc * 8];
            }
        }
        f32x4 sacc = (f32x4){0.f, 0.f, 0.f, 0.f};
        #pragma unroll
        for (int f = 0; f < 4; f++) {
            int cidx = wave * 16 + f * 4 + quad;
            bf16x8 kf = *(const bf16x8*)&Ks[lm * 512 + (cidx ^ (lm & 7)) * 8];
            sacc = __builtin_amdgcn_mfma_f32_16x16x32_bf16(qf[f], kf, sacc, 0, 0, 0);
        }
        #pragma unroll
        for (int r = 0; r < 4; r++) part[wave][quad * 4 + r][lm] = sacc[r];
        if (wave == 3) {
            bf16x8 gkf = *(const bf16x8*)&gk_bf[(rowk0 + (long)s * 16 + lm) * RANK + quad * 8];
            f32x4 gacc = (f32x4){0.f, 0.f, 0.f, 0.f};
            gacc = __builtin_amdgcn_mfma_f32_16x16x32_bf16(gqf, gkf, gacc, 0, 0, 0);
            #pragma unroll
            for (int r = 0; r < 4; r++) Gb[quad * 4 + r][lm] = gacc[r];
        }
        __syncthreads();
        float sv = (part[0][qi][ki] + part[1][qi][ki] + part[2][qi][ki] + part[3][qi][ki]) * scale;
        float gl = Gb[qi][ki] * grs;
        float sig = 1.f / (1.f + expf(-gl));
        sv += logf(sig + 1e-6f);
        float mx = sv;
        mx = fmaxf(mx, __shfl_xor(mx, 1));
        mx = fmaxf(mx, __shfl_xor(mx, 2));
        mx = fmaxf(mx, __shfl_xor(mx, 4));
        mx = fmaxf(mx, __shfl_xor(mx, 8));
        float m_new = fmaxf(m_run, mx);
        float p = expf(sv - m_new);
        float ps = p;
        ps += __shfl_xor(ps, 1);
        ps += __shfl_xor(ps, 2);
        ps += __shfl_xor(ps, 4);
        ps += __shfl_xor(ps, 8);
        float alpha = expf(m_run - m_new);
        l_run = l_run * alpha + ps;
        m_run = m_new;
        Pb[qi * 40 + half * 16 + ki] = f2bf(p);
        if (half == 1) {
            Pb[qi * 40 + ki] = f2bf(bf2f(Pb[qi * 40 + ki]) * alpha);
        }
        bool dopv = (half == 1) || (s == nst - 1);
        if (dopv && half == 0) Pb[qi * 40 + 16 + ki] = 0;
        if (ki == 0) {
            if (half == 0) alphap[qi] = alpha;
            else           alphap[qi] *= alpha;
            if (s == nst - 1) linv[qi] = 1.f / l_run;
        }
        __syncthreads();
        if (dopv) {
            float ar[4];
            #pragma unroll
            for (int r = 0; r < 4; r++) ar[r] = alphap[quad * 4 + r];
            #pragma unroll
            for (int j = 0; j < 8; j++)
                #pragma unroll
                for (int r = 0; r < 4; r++) acc[j][r] *= ar[r];
            bf16x8 pf = *(const bf16x8*)&Pb[lm * 40 + quad * 8];
            #pragma unroll
            for (int j = 0; j < 8; j++) {
                int d = wave * 128 + j * 16 + lm;
                bf16x8 vf = *(const bf16x8*)&Vt[d * 32 + ((quad ^ (d & 3)) << 3)];
                acc[j] = __builtin_amdgcn_mfma_f32_16x16x32_bf16(pf, vf, acc[j], 0, 0, 0);
            }
            __syncthreads();
        }
    }
    float li[4];
    #pragma unroll
    for (int r = 0; r < 4; r++) li[r] = linv[quad * 4 + r];
    #pragma unroll
    for (int j = 0; j < 8; j++) {
        int d = wave * 128 + j * 16 + lm;
        #pragma unroll
        for (int r = 0; r < 4; r++)
            ctx[(rowq0 + quad * 4 + r) * DIMD + d] = f2bf(acc[j][r] * li[r]);
    }
}

// ---------------------------------------------------------------------------
extern "C" void kernel_launch(void* const* d_in, const int* in_sizes, int n_in,
                              void* d_out, int out_size, void* d_ws, size_t ws_size,
                              hipStream_t stream) {
    const float* query  = (const float*)d_in[0];
    const float* source = (const float*)d_in[1];
    const float* ctx0   = (const float*)d_in[2];
    const float* ctx1   = (const float*)d_in[3];
    // d_in[4] = mask: structurally known local window, unused
    const float* qn_g  = (const float*)d_in[5];
    const float* qn_b  = (const float*)d_in[6];
    const float* kvn_g = (const float*)d_in[7];
    const float* kvn_b = (const float*)d_in[8];
    const float* Wq = (const float*)d_in[9];   const float* bq = (const float*)d_in[10];
    const float* Wk = (const float*)d_in[11];  const float* bk = (const float*)d_in[12];
    const float* Wv = (const float*)d_in[13];  const float* bv = (const float*)d_in[14];
    const float* Wo = (const float*)d_in[15];  const float* bo = (const float*)d_in[16];
    const float* Wgq = (const float*)d_in[17];
    const float* Wgk = (const float*)d_in[18];
    const float* Wc0 = (const float*)d_in[19]; const float* bc0 = (const float*)d_in[20];
    const float* Wc1 = (const float*)d_in[21]; const float* bc1 = (const float*)d_in[22];
    const float* Wf  = (const float*)d_in[23]; const float* bfv = (const float*)d_in[24];

    // ---- workspace layout ----
    float* ws = (float*)d_ws;
    float* h      = ws;                         // 4096
    float* gamma  = h + 4096;                   // 4096
    float* beta   = gamma + 4096;               // 4096
    float* biaskv = beta + 4096;                // 1152
    float* biasq  = biaskv + 1152;              // 640
    float* mu_q   = biasq + 640;                // 8192
    float* rs_q   = mu_q + 8192;                // 8192
    u16* u = (u16*)(rs_q + 8192);
    u16* sln  = u;                 u += (long)MK * DIMD;   // LN(source) bf16
    u16* kp   = u;                 u += (long)MK * DIMD;   // k proj bf16
    u16* vp   = u;                 u += (long)MK * DIMD;   // v proj bf16
    u16* gk   = u;                 u += (long)MK * RANK;   // gate_k bf16
    u16* gq   = u;                 u += (long)MQ * RANK;   // gate_q bf16
    u16* qp   = u;                 u += (long)MQ * DIMD;   // q proj bf16
    u16* ctxb = u;                 u += (long)MQ * DIMD;   // attention output bf16
    u16* Btkv = u;                 u += 1152L * DIMD;      // [Wk^T | Wv^T | (Wk·Wgk)^T]
    u16* Btq  = u;                 u += 640L * DIMD;       // [Wq^T | (Wq·Wgq)^T]
    u16* Bto  = u;                 u += 512L * DIMD;       // Wo^T
    float* out = (float*)d_out;

    // K1: fused prep (latency bodies first, streaming last)
    prep_kernel<<<PREP_TOTAL, 256, 0, stream>>>(
        source, kvn_g, kvn_b, sln,
        query, mu_q, rs_q,
        ctx0, ctx1, Wc0, bc0, Wc1, bc1, h,
        Wk, Wv, Wq, Wo, Btkv, Btq, Bto,
        Wgk, Wgq, bk, bv, bq, biaskv, biasq);

    // K2: film_gb + kv projection GEMM
    kv_kernel<<<64 + 2304, 256, 0, stream>>>(
        h, Wf, bfv, gamma, beta, sln, Btkv, biaskv, kp, vp, gk);

    // K3: q projection GEMM (LN+FiLM inline)
    qproj_kernel<<<320, 256, 0, stream>>>(
        query, mu_q, rs_q, qn_g, qn_b, gamma, beta, Btq, biasq, qp, gq);

    // K4: flash local attention
    attn_kernel<<<BATCH * QS, 256, 0, stream>>>(qp, kp, vp, gq, gk, ctxb);

    // K5: output projection (fp32 out)
    ogemm_kernel<<<256, 256, 0, stream>>>(ctxb, Bto, bo, out);
}

// Round 5
// 354.724 us; speedup vs baseline: 1.0618x; 1.0082x over previous
//
#include <hip/hip_runtime.h>
#include <math.h>

// Problem constants
#define DIMD 512
#define QS 64
#define KS 256
#define WIN 4
#define BATCH 8
#define RANK 32
#define NQ 1024             // q tokens per batch
#define NK 4096             // kv tokens per batch
#define MQ (BATCH*NQ)       // 8192 q rows
#define MK (BATCH*NK)       // 32768 kv rows

typedef unsigned short u16;
typedef __attribute__((ext_vector_type(8))) short bf16x8;  // MFMA A/B frag (8 bf16)
typedef __attribute__((ext_vector_type(4))) float f32x4;   // MFMA C/D frag

__device__ inline u16 f2bf(float x) {
    union { float f; unsigned int u; } v; v.f = x;
    unsigned int r = v.u + 0x7FFF + ((v.u >> 16) & 1);
    return (u16)(r >> 16);
}
__device__ inline float bf2f(u16 x) {
    union { unsigned int u; float f; } v; v.u = ((unsigned int)x) << 16;
    return v.f;
}

// async global->LDS, 16 B per lane. LDS dest = wave-uniform base + lane*16.
__device__ __forceinline__ void gload16(const u16* g, u16* l) {
    __builtin_amdgcn_global_load_lds(
        (const __attribute__((address_space(1))) void*)g,
        (__attribute__((address_space(3))) void*)l, 16, 0, 0);
}

// ===========================================================================
// Device bodies
// ===========================================================================

// norm: LN(source)*g+b -> bf16. One wave handles 16 rows as a software
// pipeline: 2 rows current + 2 rows prefetched (loads in flight under the
// reduce/normalize of the current pair). ~48 data VGPRs -> compiler keeps it.
__device__ __forceinline__ void norm0_body16(
    int widx, const float* __restrict__ X, const float* __restrict__ g,
    const float* __restrict__ bb, u16* __restrict__ out)
{
    int lane = threadIdx.x & 63;
    long row0 = (long)widx * 16;
    int c = lane * 8;
    float4 g0 = *(const float4*)&g[c],  g1 = *(const float4*)&g[c + 4];
    float4 b0 = *(const float4*)&bb[c], b1 = *(const float4*)&bb[c + 4];
    const float* xp = X + row0 * DIMD + c;

    // current pair (rows 0,1)
    float4 ca0 = *(const float4*)xp;
    float4 ca1 = *(const float4*)(xp + 4);
    float4 cb0 = *(const float4*)(xp + DIMD);
    float4 cb1 = *(const float4*)(xp + DIMD + 4);

    #pragma unroll
    for (int it = 0; it < 8; it++) {
        float4 pa0, pa1, pb0, pb1;
        if (it < 7) {
            const float* np = xp + (2 * it + 2) * DIMD;
            pa0 = *(const float4*)np;
            pa1 = *(const float4*)(np + 4);
            pb0 = *(const float4*)(np + DIMD);
            pb1 = *(const float4*)(np + DIMD + 4);
        }
        float s0 = ca0.x + ca0.y + ca0.z + ca0.w + ca1.x + ca1.y + ca1.z + ca1.w;
        float q0 = ca0.x*ca0.x + ca0.y*ca0.y + ca0.z*ca0.z + ca0.w*ca0.w
                 + ca1.x*ca1.x + ca1.y*ca1.y + ca1.z*ca1.z + ca1.w*ca1.w;
        float s1 = cb0.x + cb0.y + cb0.z + cb0.w + cb1.x + cb1.y + cb1.z + cb1.w;
        float q1 = cb0.x*cb0.x + cb0.y*cb0.y + cb0.z*cb0.z + cb0.w*cb0.w
                 + cb1.x*cb1.x + cb1.y*cb1.y + cb1.z*cb1.z + cb1.w*cb1.w;
        #pragma unroll
        for (int o = 1; o < 64; o <<= 1) {
            s0 += __shfl_xor(s0, o); q0 += __shfl_xor(q0, o);
            s1 += __shfl_xor(s1, o); q1 += __shfl_xor(q1, o);
        }
        float mu0 = s0 * (1.f / DIMD);
        float rs0 = rsqrtf(q0 * (1.f / DIMD) - mu0 * mu0 + 1e-5f);
        float mu1 = s1 * (1.f / DIMD);
        float rs1 = rsqrtf(q1 * (1.f / DIMD) - mu1 * mu1 + 1e-5f);
        u16 o8[8];
        o8[0] = f2bf((ca0.x - mu0) * rs0 * g0.x + b0.x);
        o8[1] = f2bf((ca0.y - mu0) * rs0 * g0.y + b0.y);
        o8[2] = f2bf((ca0.z - mu0) * rs0 * g0.z + b0.z);
        o8[3] = f2bf((ca0.w - mu0) * rs0 * g0.w + b0.w);
        o8[4] = f2bf((ca1.x - mu0) * rs0 * g1.x + b1.x);
        o8[5] = f2bf((ca1.y - mu0) * rs0 * g1.y + b1.y);
        o8[6] = f2bf((ca1.z - mu0) * rs0 * g1.z + b1.z);
        o8[7] = f2bf((ca1.w - mu0) * rs0 * g1.w + b1.w);
        *(int4*)&out[(row0 + 2 * it) * DIMD + c] = *(const int4*)o8;
        o8[0] = f2bf((cb0.x - mu1) * rs1 * g0.x + b0.x);
        o8[1] = f2bf((cb0.y - mu1) * rs1 * g0.y + b0.y);
        o8[2] = f2bf((cb0.z - mu1) * rs1 * g0.z + b0.z);
        o8[3] = f2bf((cb0.w - mu1) * rs1 * g0.w + b0.w);
        o8[4] = f2bf((cb1.x - mu1) * rs1 * g1.x + b1.x);
        o8[5] = f2bf((cb1.y - mu1) * rs1 * g1.y + b1.y);
        o8[6] = f2bf((cb1.z - mu1) * rs1 * g1.z + b1.z);
        o8[7] = f2bf((cb1.w - mu1) * rs1 * g1.w + b1.w);
        *(int4*)&out[(row0 + 2 * it + 1) * DIMD + c] = *(const int4*)o8;
        ca0 = pa0; ca1 = pa1; cb0 = pb0; cb1 = pb1;
    }
}

// row stats for query rows: mu, rstd. Same 2+2 pipelined structure, 16 rows/wave.
__device__ __forceinline__ void stats_body16(
    int widx, const float* __restrict__ X, float* __restrict__ mu_o, float* __restrict__ rs_o)
{
    int lane = threadIdx.x & 63;
    long row0 = (long)widx * 16;
    int c = lane * 8;
    const float* xp = X + row0 * DIMD + c;

    float4 ca0 = *(const float4*)xp;
    float4 ca1 = *(const float4*)(xp + 4);
    float4 cb0 = *(const float4*)(xp + DIMD);
    float4 cb1 = *(const float4*)(xp + DIMD + 4);

    #pragma unroll
    for (int it = 0; it < 8; it++) {
        float4 pa0, pa1, pb0, pb1;
        if (it < 7) {
            const float* np = xp + (2 * it + 2) * DIMD;
            pa0 = *(const float4*)np;
            pa1 = *(const float4*)(np + 4);
            pb0 = *(const float4*)(np + DIMD);
            pb1 = *(const float4*)(np + DIMD + 4);
        }
        float s0 = ca0.x + ca0.y + ca0.z + ca0.w + ca1.x + ca1.y + ca1.z + ca1.w;
        float q0 = ca0.x*ca0.x + ca0.y*ca0.y + ca0.z*ca0.z + ca0.w*ca0.w
                 + ca1.x*ca1.x + ca1.y*ca1.y + ca1.z*ca1.z + ca1.w*ca1.w;
        float s1 = cb0.x + cb0.y + cb0.z + cb0.w + cb1.x + cb1.y + cb1.z + cb1.w;
        float q1 = cb0.x*cb0.x + cb0.y*cb0.y + cb0.z*cb0.z + cb0.w*cb0.w
                 + cb1.x*cb1.x + cb1.y*cb1.y + cb1.z*cb1.z + cb1.w*cb1.w;
        #pragma unroll
        for (int o = 1; o < 64; o <<= 1) {
            s0 += __shfl_xor(s0, o); q0 += __shfl_xor(q0, o);
            s1 += __shfl_xor(s1, o); q1 += __shfl_xor(q1, o);
        }
        if (lane == 0) {
            float mu0 = s0 * (1.f / DIMD);
            mu_o[row0 + 2 * it] = mu0;
            rs_o[row0 + 2 * it] = rsqrtf(q0 * (1.f / DIMD) - mu0 * mu0 + 1e-5f);
            float mu1 = s1 * (1.f / DIMD);
            mu_o[row0 + 2 * it + 1] = mu1;
            rs_o[row0 + 2 * it + 1] = rsqrtf(q1 * (1.f / DIMD) - mu1 * mu1 + 1e-5f);
        }
        ca0 = pa0; ca1 = pa1; cb0 = pb0; cb1 = pb1;
    }
}

// film_h: h = silu(ctx0@Wc0 + bc0 + ctx1@Wc1 + bc1), bid in [0,64)
__device__ __forceinline__ void film_h_body(
    int bid, const float* __restrict__ ctx0, const float* __restrict__ ctx1,
    const float* __restrict__ Wc0, const float* __restrict__ bc0,
    const float* __restrict__ Wc1, const float* __restrict__ bc1,
    float* __restrict__ h)
{
    int b = bid >> 3;
    int d0 = (bid & 7) * 64;
    int t = threadIdx.x;
    int dl = t >> 2, p = t & 3;
    int d = d0 + dl;
    const float* c0 = ctx0 + b * DIMD;
    const float* c1 = ctx1 + b * DIMD;
    float acc = 0.f;
    #pragma unroll 4
    for (int ii = 0; ii < 128; ii++) {
        int i = p * 128 + ii;
        acc = fmaf(c0[i], Wc0[i * DIMD + d], acc);
        acc = fmaf(c1[i], Wc1[i * DIMD + d], acc);
    }
    acc += __shfl_xor(acc, 1);
    acc += __shfl_xor(acc, 2);
    if (p == 0) {
        float v = acc + bc0[d] + bc1[d];
        h[b * DIMD + d] = v / (1.f + expf(-v));
    }
}

// film_gb: gamma,beta = split(h @ Wf + bf), bid in [0,64)
__device__ __forceinline__ void film_gb_body(
    int bid, const float* __restrict__ h, const float* __restrict__ Wf,
    const float* __restrict__ bfv, float* __restrict__ gamma, float* __restrict__ beta)
{
    int b = bid >> 3;
    int d0 = (bid & 7) * 64;
    int t = threadIdx.x;
    int dl = t >> 2, p = t & 3;
    int d = d0 + dl;
    const float* hb = h + b * DIMD;
    float ga = 0.f, be = 0.f;
    #pragma unroll 4
    for (int ii = 0; ii < 128; ii++) {
        int i = p * 128 + ii;
        float hv = hb[i];
        ga = fmaf(hv, Wf[i * 2 * DIMD + d], ga);
        be = fmaf(hv, Wf[i * 2 * DIMD + DIMD + d], be);
    }
    ga += __shfl_xor(ga, 1); ga += __shfl_xor(ga, 2);
    be += __shfl_xor(be, 1); be += __shfl_xor(be, 2);
    if (p == 0) {
        gamma[b * DIMD + d] = ga + bfv[d];
        beta[b * DIMD + d]  = be + bfv[DIMD + d];
    }
}

// transpose W[512][512] -> bf16 dst[dst_row_off + n][k], i in [0,256)
__device__ __forceinline__ void transpose_body(
    int i, const float* __restrict__ src, u16* __restrict__ dst, int dst_row_off,
    float (*tile)[33])
{
    int t = threadIdx.x;
    int tx = t & 31, ty = t >> 5;
    int bx = (i & 15) * 32;
    int by = (i >> 4) * 32;
    #pragma unroll
    for (int k = 0; k < 4; k++)
        tile[ty + k * 8][tx] = src[(long)(by + ty + k * 8) * DIMD + bx + tx];
    __syncthreads();
    #pragma unroll
    for (int k = 0; k < 4; k++)
        dst[(long)(dst_row_off + bx + ty + k * 8) * DIMD + by + tx] = f2bf(tile[tx][ty + k * 8]);
}

// gatefuse: dst[off+r][k] = sum_j W[k][j]*Wg[j][r], idx = global elem id
__device__ __forceinline__ void gatefuse_body(
    int idx, const float* __restrict__ W, const float* __restrict__ Wg,
    u16* __restrict__ dst, int dst_row_off)
{
    int r = idx & 31, k = idx >> 5;
    float acc = 0.f;
    #pragma unroll 4
    for (int j = 0; j < DIMD; j++) acc = fmaf(W[k * DIMD + j], Wg[j * RANK + r], acc);
    dst[(long)(dst_row_off + r) * DIMD + k] = f2bf(acc);
}

__device__ __forceinline__ void biascat3_body(
    int bid, const float* __restrict__ b0, const float* __restrict__ b1,
    const float* __restrict__ Wg, float* __restrict__ dst)
{
    int t = bid * 256 + threadIdx.x;
    if (t < 512) dst[t] = b0[t];
    else if (t < 1024) dst[t] = b1[t - 512];
    else if (t < 1056) {
        int r = t - 1024;
        float a = 0.f;
        #pragma unroll 4
        for (int j = 0; j < DIMD; j++) a = fmaf(b0[j], Wg[j * RANK + r], a);
        dst[t] = a;
    }
}

__device__ __forceinline__ void biascat2_body(
    int bid, const float* __restrict__ b0, const float* __restrict__ Wg,
    float* __restrict__ dst)
{
    int t = bid * 256 + threadIdx.x;
    if (t < 512) dst[t] = b0[t];
    else if (t < 544) {
        int r = t - 512;
        float a = 0.f;
        #pragma unroll 4
        for (int j = 0; j < DIMD; j++) a = fmaf(b0[j], Wg[j * RANK + r], a);
        dst[t] = a;
    }
}

// ---------------------------------------------------------------------------
// bf16 MFMA GEMM body, BK=64, XOR-swizzled LDS (both-sides: pre-swizzled
// global source col + swizzled ds_read chunk) -> conflict-free fragment reads.
// smem must be 16384 u16 (32 KB).
// ---------------------------------------------------------------------------
template<int NSEC, bool BF>
__device__ __forceinline__ void gemm_body(
    int id, const u16* __restrict__ A, const u16* __restrict__ Bt,
    const float* __restrict__ biascat,
    void* __restrict__ C0v, void* __restrict__ C1v, void* __restrict__ Cgv,
    int Nvalid, int nx, int ypg, u16* smem)
{
    u16* As = smem;           // [128][64] bf16, chunk-swizzled
    u16* Bs = smem + 8192;    // [128][64] bf16, chunk-swizzled

    int t = threadIdx.x;
    int wave = t >> 6, lane = t & 63;
    int xcd = id & 7, li = id >> 3;
    int by = xcd * ypg + li / nx;
    int bx = li % nx;
    int m0 = by * 128, n0 = bx * 128;
    int mhalf = (wave >> 1) * 64, nhalf = (wave & 1) * 64;
    int lm = lane & 15, quad = lane >> 4;

    int srow = wave * 8 + (lane >> 3);
    int scol = ((lane & 7) ^ (lane >> 3)) * 8;
    const u16* Ag = A + (long)(m0 + srow) * DIMD + scol;
    const u16* Bg = Bt + (long)(n0 + srow) * DIMD + scol;
    u16* Asl = As + wave * 512 + lane * 8;
    u16* Bsl = Bs + wave * 512 + lane * 8;

    f32x4 acc[4][4];
    #pragma unroll
    for (int i = 0; i < 4; i++)
        #pragma unroll
        for (int j = 0; j < 4; j++)
            acc[i][j] = (f32x4){0.f, 0.f, 0.f, 0.f};

    for (int k0 = 0; k0 < DIMD; k0 += 64) {
        __syncthreads();
        #pragma unroll
        for (int g = 0; g < 4; g++) {
            gload16(Ag + k0 + g * 32 * DIMD, Asl + g * 2048);
            gload16(Bg + k0 + g * 32 * DIMD, Bsl + g * 2048);
        }
        __syncthreads();
        #pragma unroll
        for (int kk = 0; kk < 2; kk++) {
            bf16x8 af[4], bfr[4];
            #pragma unroll
            for (int i = 0; i < 4; i++) {
                int pc = ((kk * 4 + quad) ^ (lm & 7)) << 3;
                af[i]  = *(const bf16x8*)&As[(mhalf + i * 16 + lm) * 64 + pc];
                bfr[i] = *(const bf16x8*)&Bs[(nhalf + i * 16 + lm) * 64 + pc];
            }
            #pragma unroll
            for (int i = 0; i < 4; i++)
                #pragma unroll
                for (int j = 0; j < 4; j++)
                    acc[i][j] = __builtin_amdgcn_mfma_f32_16x16x32_bf16(af[i], bfr[j], acc[i][j], 0, 0, 0);
        }
    }

    float biasj[4];
    #pragma unroll
    for (int j = 0; j < 4; j++) biasj[j] = biascat[n0 + nhalf + j * 16 + lm];

    if (BF) {
        #pragma unroll
        for (int p = 0; p < 2; p++) {
            __syncthreads();
            #pragma unroll
            for (int ii = 0; ii < 2; ii++) {
                int i = p * 2 + ii;
                #pragma unroll
                for (int j = 0; j < 4; j++)
                    #pragma unroll
                    for (int r = 0; r < 4; r++)
                        smem[(ii * 32 + (wave >> 1) * 16 + quad * 4 + r) * 136 + nhalf + j * 16 + lm] =
                            f2bf(acc[i][j][r] + biasj[j]);
            }
            __syncthreads();
            #pragma unroll
            for (int u = 0; u < 4; u++) {
                int cch = t + u * 256;            // 0..1023
                int R = cch >> 4, ci = cch & 15;  // R 0..63
                int i = p * 2 + (R >> 5);
                int Rr = R & 31;
                long grow = m0 + (Rr >> 4) * 64 + i * 16 + (Rr & 15);
                int gcol = n0 + ci * 8;
                int4 val = *(const int4*)&smem[R * 136 + ci * 8];
                if (NSEC == 1) {
                    *(int4*)((u16*)C0v + grow * 512 + gcol) = val;
                } else if (NSEC == 2) {
                    if (gcol < 512)          *(int4*)((u16*)C0v + grow * 512 + gcol) = val;
                    else if (gcol < Nvalid)  *(int4*)((u16*)Cgv + grow * 32 + (gcol - 512)) = val;
                } else {
                    if (gcol < 512)          *(int4*)((u16*)C0v + grow * 512 + gcol) = val;
                    else if (gcol < 1024)    *(int4*)((u16*)C1v + grow * 512 + (gcol - 512)) = val;
                    else if (gcol < Nvalid)  *(int4*)((u16*)Cgv + grow * 32 + (gcol - 1024)) = val;
                }
            }
        }
    } else {
        float* Stg = (float*)smem;   // 32*132*4B = 16.9 KB <= 32 KB
        for (int i = 0; i < 4; i++) {
            __syncthreads();
            #pragma unroll
            for (int j = 0; j < 4; j++)
                #pragma unroll
                for (int r = 0; r < 4; r++)
                    Stg[((wave >> 1) * 16 + quad * 4 + r) * 132 + nhalf + j * 16 + lm] =
                        acc[i][j][r] + biasj[j];
            __syncthreads();
            #pragma unroll
            for (int u = 0; u < 4; u++) {
                int cch = t + u * 256;
                int R = cch >> 5, ci = cch & 31;
                long grow = m0 + (R >> 4) * 64 + i * 16 + (R & 15);
                int gcol = n0 + ci * 4;
                *(float4*)((float*)C0v + grow * 512 + gcol) = *(const float4*)&Stg[R * 132 + ci * 4];
            }
        }
    }
}

// ===========================================================================
// K1: fused prep — latency-chain bodies first, streaming last.
//   [0,64)        film_h
//   [64,192)      gatefuse
//   [192,200)     biascat
//   [200,1224)    transposes
//   [1224,1352)   q stats   (16 rows/wave, pipelined)
//   [1352,1864)   norm0     (16 rows/wave, pipelined)
// ===========================================================================
#define PREP_FILMH   64
#define PREP_GATE    (PREP_FILMH + 128)    // 192
#define PREP_BIAS    (PREP_GATE + 8)       // 200
#define PREP_TRANS   (PREP_BIAS + 1024)    // 1224
#define PREP_STATS   (PREP_TRANS + 128)    // 1352
#define PREP_TOTAL   (PREP_STATS + 512)    // 1864

__global__ __launch_bounds__(256) void prep_kernel(
    const float* __restrict__ source, const float* __restrict__ kvn_g,
    const float* __restrict__ kvn_b, u16* __restrict__ sln,
    const float* __restrict__ query, float* __restrict__ mu_q, float* __restrict__ rs_q,
    const float* __restrict__ ctx0, const float* __restrict__ ctx1,
    const float* __restrict__ Wc0, const float* __restrict__ bc0,
    const float* __restrict__ Wc1, const float* __restrict__ bc1,
    float* __restrict__ h,
    const float* __restrict__ Wk, const float* __restrict__ Wv,
    const float* __restrict__ Wq, const float* __restrict__ Wo,
    u16* __restrict__ Btkv, u16* __restrict__ Btq, u16* __restrict__ Bto,
    const float* __restrict__ Wgk, const float* __restrict__ Wgq,
    const float* __restrict__ bk, const float* __restrict__ bv,
    const float* __restrict__ bq, float* __restrict__ biaskv,
    float* __restrict__ biasq)
{
    __shared__ float tile[32][33];
    int bid = blockIdx.x;
    int wave = threadIdx.x >> 6;
    if (bid < PREP_FILMH) {
        film_h_body(bid, ctx0, ctx1, Wc0, bc0, Wc1, bc1, h);
    } else if (bid < PREP_GATE) {
        int gid = bid - PREP_FILMH;
        int idx = (gid & 63) * 256 + threadIdx.x;
        if (gid < 64) gatefuse_body(idx, Wk, Wgk, Btkv, 1024);
        else          gatefuse_body(idx, Wq, Wgq, Btq, 512);
    } else if (bid < PREP_BIAS) {
        int cid = bid - PREP_GATE;
        if (cid < 5) biascat3_body(cid, bk, bv, Wgk, biaskv);
        else         biascat2_body(cid - 5, bq, Wgq, biasq);
    } else if (bid < PREP_TRANS) {
        int tid = bid - PREP_BIAS;
        int which = tid >> 8, i = tid & 255;
        if (which == 0)      transpose_body(i, Wk, Btkv, 0, tile);
        else if (which == 1) transpose_body(i, Wv, Btkv, 512, tile);
        else if (which == 2) transpose_body(i, Wq, Btq, 0, tile);
        else                 transpose_body(i, Wo, Bto, 0, tile);
    } else if (bid < PREP_STATS) {
        stats_body16((bid - PREP_TRANS) * 4 + wave, query, mu_q, rs_q);
    } else {
        norm0_body16((bid - PREP_STATS) * 4 + wave, source, kvn_g, kvn_b, sln);
    }
}

// ===========================================================================
// K2: film_gb (64 blocks) + kv projection GEMM (2304 blocks)
// ===========================================================================
__global__ __launch_bounds__(256) void kv_kernel(
    const float* __restrict__ h, const float* __restrict__ Wf,
    const float* __restrict__ bfv, float* __restrict__ gamma, float* __restrict__ beta,
    const u16* __restrict__ sln, const u16* __restrict__ Btkv,
    const float* __restrict__ biaskv,
    u16* __restrict__ kp, u16* __restrict__ vp, u16* __restrict__ gk)
{
    __shared__ u16 smem[16384];
    int bid = blockIdx.x;
    if (bid < 64) {
        film_gb_body(bid, h, Wf, bfv, gamma, beta);
    } else {
        gemm_body<3, true>(bid - 64, sln, Btkv, biaskv, kp, vp, gk, 1056, 9, 32, smem);
    }
}

// ===========================================================================
// K3: q projection GEMM with LN+FiLM fused into A-staging (BK=32, unchanged)
// ===========================================================================
__global__ __launch_bounds__(256) void qproj_kernel(
    const float* __restrict__ query, const float* __restrict__ mu_q,
    const float* __restrict__ rs_q, const float* __restrict__ qn_g,
    const float* __restrict__ qn_b, const float* __restrict__ gamma,
    const float* __restrict__ beta, const u16* __restrict__ Btq,
    const float* __restrict__ biasq, u16* __restrict__ qp, u16* __restrict__ gq)
{
    __shared__ u16 smem[8192];
    u16* As = smem;
    u16* Bs = smem + 4096;

    int t = threadIdx.x;
    int wave = t >> 6, lane = t & 63;
    int id = blockIdx.x;
    int xcd = id & 7, li = id >> 3;
    int by = xcd * 8 + li / 5;
    int bx = li % 5;
    int m0 = by * 128, n0 = bx * 128;
    int mhalf = (wave >> 1) * 64, nhalf = (wave & 1) * 64;
    int lm = lane & 15, quad = lane >> 4;
    int bt = m0 >> 10;                    // batch (128 | 1024, uniform per block)

    int srow = wave * 32 + (lane >> 2);
    int scol = (lane & 3) * 8;
    const u16* Bg = Btq + (long)(n0 + srow) * DIMD + scol;
    u16* Bsl = Bs + wave * 1024 + lane * 8;

    f32x4 acc[4][4];
    #pragma unroll
    for (int i = 0; i < 4; i++)
        #pragma unroll
        for (int j = 0; j < 4; j++)
            acc[i][j] = (f32x4){0.f, 0.f, 0.f, 0.f};

    for (int k0 = 0; k0 < DIMD; k0 += 32) {
        __syncthreads();
        gload16(Bg + k0, Bsl);
        gload16(Bg + 16 * DIMD + k0, Bsl + 512);
        // A staging: LN+FiLM inline, 2 chunks of 8 elements per thread
        #pragma unroll
        for (int u = 0; u < 2; u++) {
            int idx = t + u * 256;            // 0..511
            int r = idx >> 2;                 // row 0..127
            int c8 = (idx & 3) * 8;           // col 0,8,16,24
            long grow = m0 + r;
            int col = k0 + c8;
            const float* xp = &query[grow * DIMD + col];
            float4 x0 = *(const float4*)xp, x1 = *(const float4*)(xp + 4);
            float mu = mu_q[grow], rs = rs_q[grow];
            float4 g0 = *(const float4*)&qn_g[col], g1 = *(const float4*)&qn_g[col + 4];
            float4 b0 = *(const float4*)&qn_b[col], b1 = *(const float4*)&qn_b[col + 4];
            const float* gp = gamma + bt * DIMD + col;
            const float* bp = beta + bt * DIMD + col;
            float4 gm0 = *(const float4*)gp, gm1 = *(const float4*)(gp + 4);
            float4 be0 = *(const float4*)bp, be1 = *(const float4*)(bp + 4);
            u16 o8[8];
            o8[0] = f2bf(((x0.x - mu) * rs * g0.x + b0.x) * (1.f + gm0.x) + be0.x);
            o8[1] = f2bf(((x0.y - mu) * rs * g0.y + b0.y) * (1.f + gm0.y) + be0.y);
            o8[2] = f2bf(((x0.z - mu) * rs * g0.z + b0.z) * (1.f + gm0.z) + be0.z);
            o8[3] = f2bf(((x0.w - mu) * rs * g0.w + b0.w) * (1.f + gm0.w) + be0.w);
            o8[4] = f2bf(((x1.x - mu) * rs * g1.x + b1.x) * (1.f + gm1.x) + be1.x);
            o8[5] = f2bf(((x1.y - mu) * rs * g1.y + b1.y) * (1.f + gm1.y) + be1.y);
            o8[6] = f2bf(((x1.z - mu) * rs * g1.z + b1.z) * (1.f + gm1.z) + be1.z);
            o8[7] = f2bf(((x1.w - mu) * rs * g1.w + b1.w) * (1.f + gm1.w) + be1.w);
            *(int4*)&As[r * 32 + c8] = *(const int4*)o8;
        }
        __syncthreads();
        bf16x8 af[4], bfr[4];
        #pragma unroll
        for (int i = 0; i < 4; i++) {
            af[i]  = *(const bf16x8*)&As[(mhalf + i * 16 + lm) * 32 + quad * 8];
            bfr[i] = *(const bf16x8*)&Bs[(nhalf + i * 16 + lm) * 32 + quad * 8];
        }
        #pragma unroll
        for (int i = 0; i < 4; i++)
            #pragma unroll
            for (int j = 0; j < 4; j++)
                acc[i][j] = __builtin_amdgcn_mfma_f32_16x16x32_bf16(af[i], bfr[j], acc[i][j], 0, 0, 0);
    }

    float biasj[4];
    #pragma unroll
    for (int j = 0; j < 4; j++) biasj[j] = biasq[n0 + nhalf + j * 16 + lm];

    for (int i = 0; i < 4; i++) {
        __syncthreads();
        #pragma unroll
        for (int j = 0; j < 4; j++)
            #pragma unroll
            for (int r = 0; r < 4; r++)
                smem[((wave >> 1) * 16 + quad * 4 + r) * 128 + nhalf + j * 16 + lm] =
                    f2bf(acc[i][j][r] + biasj[j]);
        __syncthreads();
        #pragma unroll
        for (int u = 0; u < 2; u++) {
            int cch = t + u * 256;
            int R = cch >> 4, ci = cch & 15;
            long grow = m0 + (R >> 4) * 64 + i * 16 + (R & 15);
            int gcol = n0 + ci * 8;
            int4 val = *(const int4*)&smem[R * 128 + ci * 8];
            if (gcol < 512)       *(int4*)(qp + grow * 512 + gcol) = val;
            else if (gcol < 544)  *(int4*)(gq + grow * 32 + (gcol - 512)) = val;
        }
    }
}

// ===========================================================================
// K5: output projection (fp32 out)
// ===========================================================================
__global__ __launch_bounds__(256) void ogemm_kernel(
    const u16* __restrict__ ctxb, const u16* __restrict__ Bto,
    const float* __restrict__ bo, float* __restrict__ out)
{
    __shared__ u16 smem[16384];
    gemm_body<1, false>(blockIdx.x, ctxb, Bto, bo, out, nullptr, nullptr, 512, 4, 8, smem);
}

// ===========================================================================
// K4: Flash-style local attention (unchanged)
// ===========================================================================
__global__ __launch_bounds__(256, 2) void attn_kernel(
    const u16* __restrict__ q_bf, const u16* __restrict__ k_bf,
    const u16* __restrict__ v_bf, const u16* __restrict__ gq_bf,
    const u16* __restrict__ gk_bf, u16* __restrict__ ctx)
{
    __shared__ u16 Ks[16 * 512];
    __shared__ u16 Vt[512 * 32];
    __shared__ u16 Pb[16 * 40];
    __shared__ float part[4][16][16];
    __shared__ float Gb[16][16];
    __shared__ float alphap[16];
    __shared__ float linv[16];

    int blk = blockIdx.x;
    int b = blk >> 6, qs = blk & 63;
    int center = (int)(qs * (255.0f / 63.0f) + 0.5f);
    int lo = center - WIN; if (lo < 0) lo = 0;
    int hi = center + WIN; if (hi > KS - 1) hi = KS - 1;
    int nst = hi - lo + 1;
    long rowq0 = (long)b * NQ + qs * 16;
    long rowk0 = (long)b * NK + lo * 16;

    int t = threadIdx.x;
    int wave = t >> 6, lane = t & 63;
    int lm = lane & 15, quad = lane >> 4;
    int qi = t >> 4, ki = t & 15;

    bf16x8 qf[4];
    #pragma unroll
    for (int f = 0; f < 4; f++)
        qf[f] = *(const bf16x8*)&q_bf[(rowq0 + lm) * DIMD + wave * 128 + f * 32 + quad * 8];
    bf16x8 gqf;
    if (wave == 3) gqf = *(const bf16x8*)&gq_bf[(rowq0 + lm) * RANK + quad * 8];

    int4 kpre[4], vpre[4];
    #pragma unroll
    for (int u = 0; u < 4; u++) {
        int idx = u * 256 + t;
        kpre[u] = *(const int4*)&k_bf[(rowk0 + (idx >> 6)) * DIMD + (idx & 63) * 8];
        int vkv = (idx >> 2) & 15, vdc = (idx & 3) | ((idx >> 6) << 2);
        vpre[u] = *(const int4*)&v_bf[(rowk0 + vkv) * DIMD + vdc * 8];
    }

    float m_run = -1e30f, l_run = 0.f;
    f32x4 acc[8];
    #pragma unroll
    for (int j = 0; j < 8; j++) acc[j] = (f32x4){0.f, 0.f, 0.f, 0.f};

    const float scale = 0.044194173824159216f;   // 512^-0.5
    const float grs = 0.17677669529663687f;      // 32^-0.5

    for (int s = 0; s < nst; s++) {
        int half = s & 1;
        #pragma unroll
        for (int u = 0; u < 4; u++) {
            int idx = u * 256 + t;
            int row = idx >> 6, c = idx & 63;
            *(int4*)&Ks[row * 512 + (c ^ (row & 7)) * 8] = kpre[u];
            int vkv = (idx >> 2) & 15, vdc = (idx & 3) | ((idx >> 6) << 2);
            int kvp = half * 16 + vkv;
            u16 vv[8];
            *(int4*)vv = vpre[u];
            #pragma unroll
            for (int i = 0; i < 8; i++) {
                int d = vdc * 8 + i;
                Vt[d * 32 + (((kvp >> 3) ^ (d & 3)) << 3) + (kvp & 7)] = vv[i];
            }
        }
        __syncthreads();
        if (s + 1 < nst) {
            long rk = rowk0 + (long)(s + 1) * 16;
            #pragma unroll
            for (int u = 0; u < 4; u++) {
                int idx = u * 256 + t;
                kpre[u] = *(const int4*)&k_bf[(rk + (idx >> 6)) * DIMD + (idx & 63) * 8];
                int vkv = (idx >> 2) & 15, vdc = (idx & 3) | ((idx >> 6) << 2);
                vpre[u] = *(const int4*)&v_bf[(rk + vkv) * DIMD + vdc * 8];
            }
        }
        f32x4 sacc = (f32x4){0.f, 0.f, 0.f, 0.f};
        #pragma unroll
        for (int f = 0; f < 4; f++) {
            int cidx = wave * 16 + f * 4 + quad;
            bf16x8 kf = *(const bf16x8*)&Ks[lm * 512 + (cidx ^ (lm & 7)) * 8];
            sacc = __builtin_amdgcn_mfma_f32_16x16x32_bf16(qf[f], kf, sacc, 0, 0, 0);
        }
        #pragma unroll
        for (int r = 0; r < 4; r++) part[wave][quad * 4 + r][lm] = sacc[r];
        if (wave == 3) {
            bf16x8 gkf = *(const bf16x8*)&gk_bf[(rowk0 + (long)s * 16 + lm) * RANK + quad * 8];
            f32x4 gacc = (f32x4){0.f, 0.f, 0.f, 0.f};
            gacc = __builtin_amdgcn_mfma_f32_16x16x32_bf16(gqf, gkf, gacc, 0, 0, 0);
            #pragma unroll
            for (int r = 0; r < 4; r++) Gb[quad * 4 + r][lm] = gacc[r];
        }
        __syncthreads();
        float sv = (part[0][qi][ki] + part[1][qi][ki] + part[2][qi][ki] + part[3][qi][ki]) * scale;
        float gl = Gb[qi][ki] * grs;
        float sig = 1.f / (1.f + expf(-gl));
        sv += logf(sig + 1e-6f);
        float mx = sv;
        mx = fmaxf(mx, __shfl_xor(mx, 1));
        mx = fmaxf(mx, __shfl_xor(mx, 2));
        mx = fmaxf(mx, __shfl_xor(mx, 4));
        mx = fmaxf(mx, __shfl_xor(mx, 8));
        float m_new = fmaxf(m_run, mx);
        float p = expf(sv - m_new);
        float ps = p;
        ps += __shfl_xor(ps, 1);
        ps += __shfl_xor(ps, 2);
        ps += __shfl_xor(ps, 4);
        ps += __shfl_xor(ps, 8);
        float alpha = expf(m_run - m_new);
        l_run = l_run * alpha + ps;
        m_run = m_new;
        Pb[qi * 40 + half * 16 + ki] = f2bf(p);
        if (half == 1) {
            Pb[qi * 40 + ki] = f2bf(bf2f(Pb[qi * 40 + ki]) * alpha);
        }
        bool dopv = (half == 1) || (s == nst - 1);
        if (dopv && half == 0) Pb[qi * 40 + 16 + ki] = 0;
        if (ki == 0) {
            if (half == 0) alphap[qi] = alpha;
            else           alphap[qi] *= alpha;
            if (s == nst - 1) linv[qi] = 1.f / l_run;
        }
        __syncthreads();
        if (dopv) {
            float ar[4];
            #pragma unroll
            for (int r = 0; r < 4; r++) ar[r] = alphap[quad * 4 + r];
            #pragma unroll
            for (int j = 0; j < 8; j++)
                #pragma unroll
                for (int r = 0; r < 4; r++) acc[j][r] *= ar[r];
            bf16x8 pf = *(const bf16x8*)&Pb[lm * 40 + quad * 8];
            #pragma unroll
            for (int j = 0; j < 8; j++) {
                int d = wave * 128 + j * 16 + lm;
                bf16x8 vf = *(const bf16x8*)&Vt[d * 32 + ((quad ^ (d & 3)) << 3)];
                acc[j] = __builtin_amdgcn_mfma_f32_16x16x32_bf16(pf, vf, acc[j], 0, 0, 0);
            }
            __syncthreads();
        }
    }
    float li[4];
    #pragma unroll
    for (int r = 0; r < 4; r++) li[r] = linv[quad * 4 + r];
    #pragma unroll
    for (int j = 0; j < 8; j++) {
        int d = wave * 128 + j * 16 + lm;
        #pragma unroll
        for (int r = 0; r < 4; r++)
            ctx[(rowq0 + quad * 4 + r) * DIMD + d] = f2bf(acc[j][r] * li[r]);
    }
}

// ---------------------------------------------------------------------------
extern "C" void kernel_launch(void* const* d_in, const int* in_sizes, int n_in,
                              void* d_out, int out_size, void* d_ws, size_t ws_size,
                              hipStream_t stream) {
    const float* query  = (const float*)d_in[0];
    const float* source = (const float*)d_in[1];
    const float* ctx0   = (const float*)d_in[2];
    const float* ctx1   = (const float*)d_in[3];
    // d_in[4] = mask: structurally known local window, unused
    const float* qn_g  = (const float*)d_in[5];
    const float* qn_b  = (const float*)d_in[6];
    const float* kvn_g = (const float*)d_in[7];
    const float* kvn_b = (const float*)d_in[8];
    const float* Wq = (const float*)d_in[9];   const float* bq = (const float*)d_in[10];
    const float* Wk = (const float*)d_in[11];  const float* bk = (const float*)d_in[12];
    const float* Wv = (const float*)d_in[13];  const float* bv = (const float*)d_in[14];
    const float* Wo = (const float*)d_in[15];  const float* bo = (const float*)d_in[16];
    const float* Wgq = (const float*)d_in[17];
    const float* Wgk = (const float*)d_in[18];
    const float* Wc0 = (const float*)d_in[19]; const float* bc0 = (const float*)d_in[20];
    const float* Wc1 = (const float*)d_in[21]; const float* bc1 = (const float*)d_in[22];
    const float* Wf  = (const float*)d_in[23]; const float* bfv = (const float*)d_in[24];

    // ---- workspace layout ----
    float* ws = (float*)d_ws;
    float* h      = ws;                         // 4096
    float* gamma  = h + 4096;                   // 4096
    float* beta   = gamma + 4096;               // 4096
    float* biaskv = beta + 4096;                // 1152
    float* biasq  = biaskv + 1152;              // 640
    float* mu_q   = biasq + 640;                // 8192
    float* rs_q   = mu_q + 8192;                // 8192
    u16* u = (u16*)(rs_q + 8192);
    u16* sln  = u;                 u += (long)MK * DIMD;   // LN(source) bf16
    u16* kp   = u;                 u += (long)MK * DIMD;   // k proj bf16
    u16* vp   = u;                 u += (long)MK * DIMD;   // v proj bf16
    u16* gk   = u;                 u += (long)MK * RANK;   // gate_k bf16
    u16* gq   = u;                 u += (long)MQ * RANK;   // gate_q bf16
    u16* qp   = u;                 u += (long)MQ * DIMD;   // q proj bf16
    u16* ctxb = u;                 u += (long)MQ * DIMD;   // attention output bf16
    u16* Btkv = u;                 u += 1152L * DIMD;      // [Wk^T | Wv^T | (Wk·Wgk)^T]
    u16* Btq  = u;                 u += 640L * DIMD;       // [Wq^T | (Wq·Wgq)^T]
    u16* Bto  = u;                 u += 512L * DIMD;       // Wo^T
    float* out = (float*)d_out;

    // K1: fused prep (latency bodies first, streaming last, pipelined streams)
    prep_kernel<<<PREP_TOTAL, 256, 0, stream>>>(
        source, kvn_g, kvn_b, sln,
        query, mu_q, rs_q,
        ctx0, ctx1, Wc0, bc0, Wc1, bc1, h,
        Wk, Wv, Wq, Wo, Btkv, Btq, Bto,
        Wgk, Wgq, bk, bv, bq, biaskv, biasq);

    // K2: film_gb + kv projection GEMM
    kv_kernel<<<64 + 2304, 256, 0, stream>>>(
        h, Wf, bfv, gamma, beta, sln, Btkv, biaskv, kp, vp, gk);

    // K3: q projection GEMM (LN+FiLM inline)
    qproj_kernel<<<320, 256, 0, stream>>>(
        query, mu_q, rs_q, qn_g, qn_b, gamma, beta, Btq, biasq, qp, gq);

    // K4: flash local attention
    attn_kernel<<<BATCH * QS, 256, 0, stream>>>(qp, kp, vp, gq, gk, ctxb);

    // K5: output projection (fp32 out)
    ogemm_kernel<<<256, 256, 0, stream>>>(ctxb, Bto, bo, out);
}

// Round 6
// 340.019 us; speedup vs baseline: 1.1077x; 1.0432x over previous
//
#include <hip/hip_runtime.h>
#include <math.h>

// Problem constants
#define DIMD 512
#define QS 64
#define KS 256
#define WIN 4
#define BATCH 8
#define RANK 32
#define NQ 1024             // q tokens per batch
#define NK 4096             // kv tokens per batch
#define MQ (BATCH*NQ)       // 8192 q rows
#define MK (BATCH*NK)       // 32768 kv rows

typedef unsigned short u16;
typedef __attribute__((ext_vector_type(8))) short bf16x8;  // MFMA A/B frag (8 bf16)
typedef __attribute__((ext_vector_type(4))) float f32x4;   // MFMA C/D frag

__device__ inline u16 f2bf(float x) {
    union { float f; unsigned int u; } v; v.f = x;
    unsigned int r = v.u + 0x7FFF + ((v.u >> 16) & 1);
    return (u16)(r >> 16);
}
__device__ inline float bf2f(u16 x) {
    union { unsigned int u; float f; } v; v.u = ((unsigned int)x) << 16;
    return v.f;
}

// async global->LDS, 16 B per lane. LDS dest = wave-uniform base + lane*16.
__device__ __forceinline__ void gload16(const u16* g, u16* l) {
    __builtin_amdgcn_global_load_lds(
        (const __attribute__((address_space(1))) void*)g,
        (__attribute__((address_space(3))) void*)l, 16, 0, 0);
}

// ===========================================================================
// Device bodies
// ===========================================================================

// stage row r (512 f32) into per-wave LDS slot (r&3): two 1KB global_load_lds
__device__ __forceinline__ void stage_row(const float* src, int r, float* ldsw, int lane) {
    const float* s_ = src + r * DIMD + lane * 4;
    float* d_ = ldsw + (r & 3) * 512;
    gload16((const u16*)s_, (u16*)(d_ + lane * 4));
    gload16((const u16*)(s_ + 256), (u16*)(d_ + 256 + lane * 4));
}

#define WAITV(n) asm volatile("s_waitcnt vmcnt(" #n ")" ::: "memory")

// Streaming LN over 16 rows/wave with an LDS-staged, vmcnt-counted pipeline.
// Pipeline depth 4 rows (8 gloads, 8KB) held in the HW vmcnt queue — the
// compiler cannot serialize it. WRITE_OUT: write LN(x)*g+b as bf16; else
// write per-row mu/rstd only.
// vmcnt ladder: each iter issues 2 stores + (r+4<16 ? 2 stage-loads : 0)
// AFTER the wait; row r's 2 loads were issued 4 iters earlier. Ops issued
// after row r's loads (in-order vmcnt retirement):
//   r=0:6  r=1:8  r=2:10  r=3..12:12  r=13:10  r=14:8  r=15:6
template<bool WRITE_OUT>
__device__ __forceinline__ void norm_staged16(
    int widx, const float* __restrict__ X, const float* __restrict__ g,
    const float* __restrict__ bb, u16* __restrict__ out,
    float* __restrict__ mu_o, float* __restrict__ rs_o, float* ldsw)
{
    int lane = threadIdx.x & 63;
    long row0 = (long)widx * 16;

    float4 g0, g1, b0, b1;
    if (WRITE_OUT) {
        g0 = *(const float4*)&g[lane * 4];
        g1 = *(const float4*)&g[256 + lane * 4];
        b0 = *(const float4*)&bb[lane * 4];
        b1 = *(const float4*)&bb[256 + lane * 4];
    }
    // retire any prior vmem (incl. gamma/beta loads) so the ladder count is exact
    WAITV(0);
    __builtin_amdgcn_sched_barrier(0);

    const float* src = X + row0 * DIMD;

    // prologue: rows 0..3 -> 8 loads outstanding
    stage_row(src, 0, ldsw, lane);
    stage_row(src, 1, ldsw, lane);
    stage_row(src, 2, ldsw, lane);
    stage_row(src, 3, ldsw, lane);

    #pragma unroll
    for (int r = 0; r < 16; r++) {
        if (r == 0 || r == 15)      WAITV(6);
        else if (r == 1 || r == 14) WAITV(8);
        else if (r == 2 || r == 13) WAITV(10);
        else                        WAITV(12);
        __builtin_amdgcn_sched_barrier(0);

        const float* rowp = ldsw + (r & 3) * 512;
        float4 a = *(const float4*)&rowp[lane * 4];
        float4 b = *(const float4*)&rowp[256 + lane * 4];

        float s = a.x + a.y + a.z + a.w + b.x + b.y + b.z + b.w;
        float q = a.x*a.x + a.y*a.y + a.z*a.z + a.w*a.w
                + b.x*b.x + b.y*b.y + b.z*b.z + b.w*b.w;
        #pragma unroll
        for (int o = 1; o < 64; o <<= 1) {
            s += __shfl_xor(s, o);
            q += __shfl_xor(q, o);
        }
        float mu = s * (1.f / DIMD);
        float rs = rsqrtf(q * (1.f / DIMD) - mu * mu + 1e-5f);

        if (WRITE_OUT) {
            u16 o4[4];
            o4[0] = f2bf((a.x - mu) * rs * g0.x + b0.x);
            o4[1] = f2bf((a.y - mu) * rs * g0.y + b0.y);
            o4[2] = f2bf((a.z - mu) * rs * g0.z + b0.z);
            o4[3] = f2bf((a.w - mu) * rs * g0.w + b0.w);
            *(int2*)&out[(row0 + r) * DIMD + lane * 4] = *(const int2*)o4;
            o4[0] = f2bf((b.x - mu) * rs * g1.x + b1.x);
            o4[1] = f2bf((b.y - mu) * rs * g1.y + b1.y);
            o4[2] = f2bf((b.z - mu) * rs * g1.z + b1.z);
            o4[3] = f2bf((b.w - mu) * rs * g1.w + b1.w);
            *(int2*)&out[(row0 + r) * DIMD + 256 + lane * 4] = *(const int2*)o4;
        } else {
            if (lane == 0) {
                mu_o[row0 + r] = mu;
                rs_o[row0 + r] = rs;
            }
        }
        if (r + 4 < 16) stage_row(src, r + 4, ldsw, lane);
    }
}

// film_h: h = silu(ctx0@Wc0 + bc0 + ctx1@Wc1 + bc1), bid in [0,64)
__device__ __forceinline__ void film_h_body(
    int bid, const float* __restrict__ ctx0, const float* __restrict__ ctx1,
    const float* __restrict__ Wc0, const float* __restrict__ bc0,
    const float* __restrict__ Wc1, const float* __restrict__ bc1,
    float* __restrict__ h)
{
    int b = bid >> 3;
    int d0 = (bid & 7) * 64;
    int t = threadIdx.x;
    int dl = t >> 2, p = t & 3;
    int d = d0 + dl;
    const float* c0 = ctx0 + b * DIMD;
    const float* c1 = ctx1 + b * DIMD;
    float acc = 0.f;
    #pragma unroll 4
    for (int ii = 0; ii < 128; ii++) {
        int i = p * 128 + ii;
        acc = fmaf(c0[i], Wc0[i * DIMD + d], acc);
        acc = fmaf(c1[i], Wc1[i * DIMD + d], acc);
    }
    acc += __shfl_xor(acc, 1);
    acc += __shfl_xor(acc, 2);
    if (p == 0) {
        float v = acc + bc0[d] + bc1[d];
        h[b * DIMD + d] = v / (1.f + expf(-v));
    }
}

// film_gb: gamma,beta = split(h @ Wf + bf), bid in [0,64)
__device__ __forceinline__ void film_gb_body(
    int bid, const float* __restrict__ h, const float* __restrict__ Wf,
    const float* __restrict__ bfv, float* __restrict__ gamma, float* __restrict__ beta)
{
    int b = bid >> 3;
    int d0 = (bid & 7) * 64;
    int t = threadIdx.x;
    int dl = t >> 2, p = t & 3;
    int d = d0 + dl;
    const float* hb = h + b * DIMD;
    float ga = 0.f, be = 0.f;
    #pragma unroll 4
    for (int ii = 0; ii < 128; ii++) {
        int i = p * 128 + ii;
        float hv = hb[i];
        ga = fmaf(hv, Wf[i * 2 * DIMD + d], ga);
        be = fmaf(hv, Wf[i * 2 * DIMD + DIMD + d], be);
    }
    ga += __shfl_xor(ga, 1); ga += __shfl_xor(ga, 2);
    be += __shfl_xor(be, 1); be += __shfl_xor(be, 2);
    if (p == 0) {
        gamma[b * DIMD + d] = ga + bfv[d];
        beta[b * DIMD + d]  = be + bfv[DIMD + d];
    }
}

// transpose W[512][512] -> bf16 dst[dst_row_off + n][k], i in [0,256)
__device__ __forceinline__ void transpose_body(
    int i, const float* __restrict__ src, u16* __restrict__ dst, int dst_row_off,
    float (*tile)[33])
{
    int t = threadIdx.x;
    int tx = t & 31, ty = t >> 5;
    int bx = (i & 15) * 32;
    int by = (i >> 4) * 32;
    #pragma unroll
    for (int k = 0; k < 4; k++)
        tile[ty + k * 8][tx] = src[(long)(by + ty + k * 8) * DIMD + bx + tx];
    __syncthreads();
    #pragma unroll
    for (int k = 0; k < 4; k++)
        dst[(long)(dst_row_off + bx + ty + k * 8) * DIMD + by + tx] = f2bf(tile[tx][ty + k * 8]);
}

// gatefuse: dst[off+r][k] = sum_j W[k][j]*Wg[j][r], idx = global elem id
__device__ __forceinline__ void gatefuse_body(
    int idx, const float* __restrict__ W, const float* __restrict__ Wg,
    u16* __restrict__ dst, int dst_row_off)
{
    int r = idx & 31, k = idx >> 5;
    float acc = 0.f;
    #pragma unroll 4
    for (int j = 0; j < DIMD; j++) acc = fmaf(W[k * DIMD + j], Wg[j * RANK + r], acc);
    dst[(long)(dst_row_off + r) * DIMD + k] = f2bf(acc);
}

__device__ __forceinline__ void biascat3_body(
    int bid, const float* __restrict__ b0, const float* __restrict__ b1,
    const float* __restrict__ Wg, float* __restrict__ dst)
{
    int t = bid * 256 + threadIdx.x;
    if (t < 512) dst[t] = b0[t];
    else if (t < 1024) dst[t] = b1[t - 512];
    else if (t < 1056) {
        int r = t - 1024;
        float a = 0.f;
        #pragma unroll 4
        for (int j = 0; j < DIMD; j++) a = fmaf(b0[j], Wg[j * RANK + r], a);
        dst[t] = a;
    }
}

__device__ __forceinline__ void biascat2_body(
    int bid, const float* __restrict__ b0, const float* __restrict__ Wg,
    float* __restrict__ dst)
{
    int t = bid * 256 + threadIdx.x;
    if (t < 512) dst[t] = b0[t];
    else if (t < 544) {
        int r = t - 512;
        float a = 0.f;
        #pragma unroll 4
        for (int j = 0; j < DIMD; j++) a = fmaf(b0[j], Wg[j * RANK + r], a);
        dst[t] = a;
    }
}

// ---------------------------------------------------------------------------
// bf16 MFMA GEMM body, BK=64, XOR-swizzled LDS (both-sides: pre-swizzled
// global source col + swizzled ds_read chunk) -> conflict-free fragment reads.
// smem must be 16384 u16 (32 KB).
// ---------------------------------------------------------------------------
template<int NSEC, bool BF>
__device__ __forceinline__ void gemm_body(
    int id, const u16* __restrict__ A, const u16* __restrict__ Bt,
    const float* __restrict__ biascat,
    void* __restrict__ C0v, void* __restrict__ C1v, void* __restrict__ Cgv,
    int Nvalid, int nx, int ypg, u16* smem)
{
    u16* As = smem;           // [128][64] bf16, chunk-swizzled
    u16* Bs = smem + 8192;    // [128][64] bf16, chunk-swizzled

    int t = threadIdx.x;
    int wave = t >> 6, lane = t & 63;
    int xcd = id & 7, li = id >> 3;
    int by = xcd * ypg + li / nx;
    int bx = li % nx;
    int m0 = by * 128, n0 = bx * 128;
    int mhalf = (wave >> 1) * 64, nhalf = (wave & 1) * 64;
    int lm = lane & 15, quad = lane >> 4;

    int srow = wave * 8 + (lane >> 3);
    int scol = ((lane & 7) ^ (lane >> 3)) * 8;
    const u16* Ag = A + (long)(m0 + srow) * DIMD + scol;
    const u16* Bg = Bt + (long)(n0 + srow) * DIMD + scol;
    u16* Asl = As + wave * 512 + lane * 8;
    u16* Bsl = Bs + wave * 512 + lane * 8;

    f32x4 acc[4][4];
    #pragma unroll
    for (int i = 0; i < 4; i++)
        #pragma unroll
        for (int j = 0; j < 4; j++)
            acc[i][j] = (f32x4){0.f, 0.f, 0.f, 0.f};

    for (int k0 = 0; k0 < DIMD; k0 += 64) {
        __syncthreads();
        #pragma unroll
        for (int g = 0; g < 4; g++) {
            gload16(Ag + k0 + g * 32 * DIMD, Asl + g * 2048);
            gload16(Bg + k0 + g * 32 * DIMD, Bsl + g * 2048);
        }
        __syncthreads();
        #pragma unroll
        for (int kk = 0; kk < 2; kk++) {
            bf16x8 af[4], bfr[4];
            #pragma unroll
            for (int i = 0; i < 4; i++) {
                int pc = ((kk * 4 + quad) ^ (lm & 7)) << 3;
                af[i]  = *(const bf16x8*)&As[(mhalf + i * 16 + lm) * 64 + pc];
                bfr[i] = *(const bf16x8*)&Bs[(nhalf + i * 16 + lm) * 64 + pc];
            }
            #pragma unroll
            for (int i = 0; i < 4; i++)
                #pragma unroll
                for (int j = 0; j < 4; j++)
                    acc[i][j] = __builtin_amdgcn_mfma_f32_16x16x32_bf16(af[i], bfr[j], acc[i][j], 0, 0, 0);
        }
    }

    float biasj[4];
    #pragma unroll
    for (int j = 0; j < 4; j++) biasj[j] = biascat[n0 + nhalf + j * 16 + lm];

    if (BF) {
        #pragma unroll
        for (int p = 0; p < 2; p++) {
            __syncthreads();
            #pragma unroll
            for (int ii = 0; ii < 2; ii++) {
                int i = p * 2 + ii;
                #pragma unroll
                for (int j = 0; j < 4; j++)
                    #pragma unroll
                    for (int r = 0; r < 4; r++)
                        smem[(ii * 32 + (wave >> 1) * 16 + quad * 4 + r) * 136 + nhalf + j * 16 + lm] =
                            f2bf(acc[i][j][r] + biasj[j]);
            }
            __syncthreads();
            #pragma unroll
            for (int u = 0; u < 4; u++) {
                int cch = t + u * 256;            // 0..1023
                int R = cch >> 4, ci = cch & 15;  // R 0..63
                int i = p * 2 + (R >> 5);
                int Rr = R & 31;
                long grow = m0 + (Rr >> 4) * 64 + i * 16 + (Rr & 15);
                int gcol = n0 + ci * 8;
                int4 val = *(const int4*)&smem[R * 136 + ci * 8];
                if (NSEC == 1) {
                    *(int4*)((u16*)C0v + grow * 512 + gcol) = val;
                } else if (NSEC == 2) {
                    if (gcol < 512)          *(int4*)((u16*)C0v + grow * 512 + gcol) = val;
                    else if (gcol < Nvalid)  *(int4*)((u16*)Cgv + grow * 32 + (gcol - 512)) = val;
                } else {
                    if (gcol < 512)          *(int4*)((u16*)C0v + grow * 512 + gcol) = val;
                    else if (gcol < 1024)    *(int4*)((u16*)C1v + grow * 512 + (gcol - 512)) = val;
                    else if (gcol < Nvalid)  *(int4*)((u16*)Cgv + grow * 32 + (gcol - 1024)) = val;
                }
            }
        }
    } else {
        float* Stg = (float*)smem;   // 32*132*4B = 16.9 KB <= 32 KB
        for (int i = 0; i < 4; i++) {
            __syncthreads();
            #pragma unroll
            for (int j = 0; j < 4; j++)
                #pragma unroll
                for (int r = 0; r < 4; r++)
                    Stg[((wave >> 1) * 16 + quad * 4 + r) * 132 + nhalf + j * 16 + lm] =
                        acc[i][j][r] + biasj[j];
            __syncthreads();
            #pragma unroll
            for (int u = 0; u < 4; u++) {
                int cch = t + u * 256;
                int R = cch >> 5, ci = cch & 31;
                long grow = m0 + (R >> 4) * 64 + i * 16 + (R & 15);
                int gcol = n0 + ci * 4;
                *(float4*)((float*)C0v + grow * 512 + gcol) = *(const float4*)&Stg[R * 132 + ci * 4];
            }
        }
    }
}

// ===========================================================================
// K1: fused prep — latency-chain bodies first, streaming last.
//   [0,64)        film_h
//   [64,192)      gatefuse
//   [192,200)     biascat
//   [200,1224)    transposes
//   [1224,1352)   q stats   (16 rows/wave, LDS-staged pipeline)
//   [1352,1864)   norm0     (16 rows/wave, LDS-staged pipeline)
// ===========================================================================
#define PREP_FILMH   64
#define PREP_GATE    (PREP_FILMH + 128)    // 192
#define PREP_BIAS    (PREP_GATE + 8)       // 200
#define PREP_TRANS   (PREP_BIAS + 1024)    // 1224
#define PREP_STATS   (PREP_TRANS + 128)    // 1352
#define PREP_TOTAL   (PREP_STATS + 512)    // 1864

__global__ __launch_bounds__(256) void prep_kernel(
    const float* __restrict__ source, const float* __restrict__ kvn_g,
    const float* __restrict__ kvn_b, u16* __restrict__ sln,
    const float* __restrict__ query, float* __restrict__ mu_q, float* __restrict__ rs_q,
    const float* __restrict__ ctx0, const float* __restrict__ ctx1,
    const float* __restrict__ Wc0, const float* __restrict__ bc0,
    const float* __restrict__ Wc1, const float* __restrict__ bc1,
    float* __restrict__ h,
    const float* __restrict__ Wk, const float* __restrict__ Wv,
    const float* __restrict__ Wq, const float* __restrict__ Wo,
    u16* __restrict__ Btkv, u16* __restrict__ Btq, u16* __restrict__ Bto,
    const float* __restrict__ Wgk, const float* __restrict__ Wgq,
    const float* __restrict__ bk, const float* __restrict__ bv,
    const float* __restrict__ bq, float* __restrict__ biaskv,
    float* __restrict__ biasq)
{
    __shared__ float tile[32][33];
    __shared__ float stg[4][2048];     // 8KB per-wave staging (4 row-slots)
    int bid = blockIdx.x;
    int wave = threadIdx.x >> 6;
    if (bid < PREP_FILMH) {
        film_h_body(bid, ctx0, ctx1, Wc0, bc0, Wc1, bc1, h);
    } else if (bid < PREP_GATE) {
        int gid = bid - PREP_FILMH;
        int idx = (gid & 63) * 256 + threadIdx.x;
        if (gid < 64) gatefuse_body(idx, Wk, Wgk, Btkv, 1024);
        else          gatefuse_body(idx, Wq, Wgq, Btq, 512);
    } else if (bid < PREP_BIAS) {
        int cid = bid - PREP_GATE;
        if (cid < 5) biascat3_body(cid, bk, bv, Wgk, biaskv);
        else         biascat2_body(cid - 5, bq, Wgq, biasq);
    } else if (bid < PREP_TRANS) {
        int tid = bid - PREP_BIAS;
        int which = tid >> 8, i = tid & 255;
        if (which == 0)      transpose_body(i, Wk, Btkv, 0, tile);
        else if (which == 1) transpose_body(i, Wv, Btkv, 512, tile);
        else if (which == 2) transpose_body(i, Wq, Btq, 0, tile);
        else                 transpose_body(i, Wo, Bto, 0, tile);
    } else if (bid < PREP_STATS) {
        norm_staged16<false>((bid - PREP_TRANS) * 4 + wave, query,
                             nullptr, nullptr, nullptr, mu_q, rs_q, stg[wave]);
    } else {
        norm_staged16<true>((bid - PREP_STATS) * 4 + wave, source,
                            kvn_g, kvn_b, sln, nullptr, nullptr, stg[wave]);
    }
}

// ===========================================================================
// K2: film_gb (64 blocks) + kv projection GEMM (2304 blocks)
// ===========================================================================
__global__ __launch_bounds__(256) void kv_kernel(
    const float* __restrict__ h, const float* __restrict__ Wf,
    const float* __restrict__ bfv, float* __restrict__ gamma, float* __restrict__ beta,
    const u16* __restrict__ sln, const u16* __restrict__ Btkv,
    const float* __restrict__ biaskv,
    u16* __restrict__ kp, u16* __restrict__ vp, u16* __restrict__ gk)
{
    __shared__ u16 smem[16384];
    int bid = blockIdx.x;
    if (bid < 64) {
        film_gb_body(bid, h, Wf, bfv, gamma, beta);
    } else {
        gemm_body<3, true>(bid - 64, sln, Btkv, biaskv, kp, vp, gk, 1056, 9, 32, smem);
    }
}

// ===========================================================================
// K3: q projection GEMM with LN+FiLM fused into A-staging (BK=32, unchanged)
// ===========================================================================
__global__ __launch_bounds__(256) void qproj_kernel(
    const float* __restrict__ query, const float* __restrict__ mu_q,
    const float* __restrict__ rs_q, const float* __restrict__ qn_g,
    const float* __restrict__ qn_b, const float* __restrict__ gamma,
    const float* __restrict__ beta, const u16* __restrict__ Btq,
    const float* __restrict__ biasq, u16* __restrict__ qp, u16* __restrict__ gq)
{
    __shared__ u16 smem[8192];
    u16* As = smem;
    u16* Bs = smem + 4096;

    int t = threadIdx.x;
    int wave = t >> 6, lane = t & 63;
    int id = blockIdx.x;
    int xcd = id & 7, li = id >> 3;
    int by = xcd * 8 + li / 5;
    int bx = li % 5;
    int m0 = by * 128, n0 = bx * 128;
    int mhalf = (wave >> 1) * 64, nhalf = (wave & 1) * 64;
    int lm = lane & 15, quad = lane >> 4;
    int bt = m0 >> 10;                    // batch (128 | 1024, uniform per block)

    int srow = wave * 32 + (lane >> 2);
    int scol = (lane & 3) * 8;
    const u16* Bg = Btq + (long)(n0 + srow) * DIMD + scol;
    u16* Bsl = Bs + wave * 1024 + lane * 8;

    f32x4 acc[4][4];
    #pragma unroll
    for (int i = 0; i < 4; i++)
        #pragma unroll
        for (int j = 0; j < 4; j++)
            acc[i][j] = (f32x4){0.f, 0.f, 0.f, 0.f};

    for (int k0 = 0; k0 < DIMD; k0 += 32) {
        __syncthreads();
        gload16(Bg + k0, Bsl);
        gload16(Bg + 16 * DIMD + k0, Bsl + 512);
        // A staging: LN+FiLM inline, 2 chunks of 8 elements per thread
        #pragma unroll
        for (int u = 0; u < 2; u++) {
            int idx = t + u * 256;            // 0..511
            int r = idx >> 2;                 // row 0..127
            int c8 = (idx & 3) * 8;           // col 0,8,16,24
            long grow = m0 + r;
            int col = k0 + c8;
            const float* xp = &query[grow * DIMD + col];
            float4 x0 = *(const float4*)xp, x1 = *(const float4*)(xp + 4);
            float mu = mu_q[grow], rs = rs_q[grow];
            float4 g0 = *(const float4*)&qn_g[col], g1 = *(const float4*)&qn_g[col + 4];
            float4 b0 = *(const float4*)&qn_b[col], b1 = *(const float4*)&qn_b[col + 4];
            const float* gp = gamma + bt * DIMD + col;
            const float* bp = beta + bt * DIMD + col;
            float4 gm0 = *(const float4*)gp, gm1 = *(const float4*)(gp + 4);
            float4 be0 = *(const float4*)bp, be1 = *(const float4*)(bp + 4);
            u16 o8[8];
            o8[0] = f2bf(((x0.x - mu) * rs * g0.x + b0.x) * (1.f + gm0.x) + be0.x);
            o8[1] = f2bf(((x0.y - mu) * rs * g0.y + b0.y) * (1.f + gm0.y) + be0.y);
            o8[2] = f2bf(((x0.z - mu) * rs * g0.z + b0.z) * (1.f + gm0.z) + be0.z);
            o8[3] = f2bf(((x0.w - mu) * rs * g0.w + b0.w) * (1.f + gm0.w) + be0.w);
            o8[4] = f2bf(((x1.x - mu) * rs * g1.x + b1.x) * (1.f + gm1.x) + be1.x);
            o8[5] = f2bf(((x1.y - mu) * rs * g1.y + b1.y) * (1.f + gm1.y) + be1.y);
            o8[6] = f2bf(((x1.z - mu) * rs * g1.z + b1.z) * (1.f + gm1.z) + be1.z);
            o8[7] = f2bf(((x1.w - mu) * rs * g1.w + b1.w) * (1.f + gm1.w) + be1.w);
            *(int4*)&As[r * 32 + c8] = *(const int4*)o8;
        }
        __syncthreads();
        bf16x8 af[4], bfr[4];
        #pragma unroll
        for (int i = 0; i < 4; i++) {
            af[i]  = *(const bf16x8*)&As[(mhalf + i * 16 + lm) * 32 + quad * 8];
            bfr[i] = *(const bf16x8*)&Bs[(nhalf + i * 16 + lm) * 32 + quad * 8];
        }
        #pragma unroll
        for (int i = 0; i < 4; i++)
            #pragma unroll
            for (int j = 0; j < 4; j++)
                acc[i][j] = __builtin_amdgcn_mfma_f32_16x16x32_bf16(af[i], bfr[j], acc[i][j], 0, 0, 0);
    }

    float biasj[4];
    #pragma unroll
    for (int j = 0; j < 4; j++) biasj[j] = biasq[n0 + nhalf + j * 16 + lm];

    for (int i = 0; i < 4; i++) {
        __syncthreads();
        #pragma unroll
        for (int j = 0; j < 4; j++)
            #pragma unroll
            for (int r = 0; r < 4; r++)
                smem[((wave >> 1) * 16 + quad * 4 + r) * 128 + nhalf + j * 16 + lm] =
                    f2bf(acc[i][j][r] + biasj[j]);
        __syncthreads();
        #pragma unroll
        for (int u = 0; u < 2; u++) {
            int cch = t + u * 256;
            int R = cch >> 4, ci = cch & 15;
            long grow = m0 + (R >> 4) * 64 + i * 16 + (R & 15);
            int gcol = n0 + ci * 8;
            int4 val = *(const int4*)&smem[R * 128 + ci * 8];
            if (gcol < 512)       *(int4*)(qp + grow * 512 + gcol) = val;
            else if (gcol < 544)  *(int4*)(gq + grow * 32 + (gcol - 512)) = val;
        }
    }
}

// ===========================================================================
// K5: output projection (fp32 out)
// ===========================================================================
__global__ __launch_bounds__(256) void ogemm_kernel(
    const u16* __restrict__ ctxb, const u16* __restrict__ Bto,
    const float* __restrict__ bo, float* __restrict__ out)
{
    __shared__ u16 smem[16384];
    gemm_body<1, false>(blockIdx.x, ctxb, Bto, bo, out, nullptr, nullptr, 512, 4, 8, smem);
}

// ===========================================================================
// K4: Flash-style local attention (unchanged)
// ===========================================================================
__global__ __launch_bounds__(256, 2) void attn_kernel(
    const u16* __restrict__ q_bf, const u16* __restrict__ k_bf,
    const u16* __restrict__ v_bf, const u16* __restrict__ gq_bf,
    const u16* __restrict__ gk_bf, u16* __restrict__ ctx)
{
    __shared__ u16 Ks[16 * 512];
    __shared__ u16 Vt[512 * 32];
    __shared__ u16 Pb[16 * 40];
    __shared__ float part[4][16][16];
    __shared__ float Gb[16][16];
    __shared__ float alphap[16];
    __shared__ float linv[16];

    int blk = blockIdx.x;
    int b = blk >> 6, qs = blk & 63;
    int center = (int)(qs * (255.0f / 63.0f) + 0.5f);
    int lo = center - WIN; if (lo < 0) lo = 0;
    int hi = center + WIN; if (hi > KS - 1) hi = KS - 1;
    int nst = hi - lo + 1;
    long rowq0 = (long)b * NQ + qs * 16;
    long rowk0 = (long)b * NK + lo * 16;

    int t = threadIdx.x;
    int wave = t >> 6, lane = t & 63;
    int lm = lane & 15, quad = lane >> 4;
    int qi = t >> 4, ki = t & 15;

    bf16x8 qf[4];
    #pragma unroll
    for (int f = 0; f < 4; f++)
        qf[f] = *(const bf16x8*)&q_bf[(rowq0 + lm) * DIMD + wave * 128 + f * 32 + quad * 8];
    bf16x8 gqf;
    if (wave == 3) gqf = *(const bf16x8*)&gq_bf[(rowq0 + lm) * RANK + quad * 8];

    int4 kpre[4], vpre[4];
    #pragma unroll
    for (int u = 0; u < 4; u++) {
        int idx = u * 256 + t;
        kpre[u] = *(const int4*)&k_bf[(rowk0 + (idx >> 6)) * DIMD + (idx & 63) * 8];
        int vkv = (idx >> 2) & 15, vdc = (idx & 3) | ((idx >> 6) << 2);
        vpre[u] = *(const int4*)&v_bf[(rowk0 + vkv) * DIMD + vdc * 8];
    }

    float m_run = -1e30f, l_run = 0.f;
    f32x4 acc[8];
    #pragma unroll
    for (int j = 0; j < 8; j++) acc[j] = (f32x4){0.f, 0.f, 0.f, 0.f};

    const float scale = 0.044194173824159216f;   // 512^-0.5
    const float grs = 0.17677669529663687f;      // 32^-0.5

    for (int s = 0; s < nst; s++) {
        int half = s & 1;
        #pragma unroll
        for (int u = 0; u < 4; u++) {
            int idx = u * 256 + t;
            int row = idx >> 6, c = idx & 63;
            *(int4*)&Ks[row * 512 + (c ^ (row & 7)) * 8] = kpre[u];
            int vkv = (idx >> 2) & 15, vdc = (idx & 3) | ((idx >> 6) << 2);
            int kvp = half * 16 + vkv;
            u16 vv[8];
            *(int4*)vv = vpre[u];
            #pragma unroll
            for (int i = 0; i < 8; i++) {
                int d = vdc * 8 + i;
                Vt[d * 32 + (((kvp >> 3) ^ (d & 3)) << 3) + (kvp & 7)] = vv[i];
            }
        }
        __syncthreads();
        if (s + 1 < nst) {
            long rk = rowk0 + (long)(s + 1) * 16;
            #pragma unroll
            for (int u = 0; u < 4; u++) {
                int idx = u * 256 + t;
                kpre[u] = *(const int4*)&k_bf[(rk + (idx >> 6)) * DIMD + (idx & 63) * 8];
                int vkv = (idx >> 2) & 15, vdc = (idx & 3) | ((idx >> 6) << 2);
                vpre[u] = *(const int4*)&v_bf[(rk + vkv) * DIMD + vdc * 8];
            }
        }
        f32x4 sacc = (f32x4){0.f, 0.f, 0.f, 0.f};
        #pragma unroll
        for (int f = 0; f < 4; f++) {
            int cidx = wave * 16 + f * 4 + quad;
            bf16x8 kf = *(const bf16x8*)&Ks[lm * 512 + (cidx ^ (lm & 7)) * 8];
            sacc = __builtin_amdgcn_mfma_f32_16x16x32_bf16(qf[f], kf, sacc, 0, 0, 0);
        }
        #pragma unroll
        for (int r = 0; r < 4; r++) part[wave][quad * 4 + r][lm] = sacc[r];
        if (wave == 3) {
            bf16x8 gkf = *(const bf16x8*)&gk_bf[(rowk0 + (long)s * 16 + lm) * RANK + quad * 8];
            f32x4 gacc = (f32x4){0.f, 0.f, 0.f, 0.f};
            gacc = __builtin_amdgcn_mfma_f32_16x16x32_bf16(gqf, gkf, gacc, 0, 0, 0);
            #pragma unroll
            for (int r = 0; r < 4; r++) Gb[quad * 4 + r][lm] = gacc[r];
        }
        __syncthreads();
        float sv = (part[0][qi][ki] + part[1][qi][ki] + part[2][qi][ki] + part[3][qi][ki]) * scale;
        float gl = Gb[qi][ki] * grs;
        float sig = 1.f / (1.f + expf(-gl));
        sv += logf(sig + 1e-6f);
        float mx = sv;
        mx = fmaxf(mx, __shfl_xor(mx, 1));
        mx = fmaxf(mx, __shfl_xor(mx, 2));
        mx = fmaxf(mx, __shfl_xor(mx, 4));
        mx = fmaxf(mx, __shfl_xor(mx, 8));
        float m_new = fmaxf(m_run, mx);
        float p = expf(sv - m_new);
        float ps = p;
        ps += __shfl_xor(ps, 1);
        ps += __shfl_xor(ps, 2);
        ps += __shfl_xor(ps, 4);
        ps += __shfl_xor(ps, 8);
        float alpha = expf(m_run - m_new);
        l_run = l_run * alpha + ps;
        m_run = m_new;
        Pb[qi * 40 + half * 16 + ki] = f2bf(p);
        if (half == 1) {
            Pb[qi * 40 + ki] = f2bf(bf2f(Pb[qi * 40 + ki]) * alpha);
        }
        bool dopv = (half == 1) || (s == nst - 1);
        if (dopv && half == 0) Pb[qi * 40 + 16 + ki] = 0;
        if (ki == 0) {
            if (half == 0) alphap[qi] = alpha;
            else           alphap[qi] *= alpha;
            if (s == nst - 1) linv[qi] = 1.f / l_run;
        }
        __syncthreads();
        if (dopv) {
            float ar[4];
            #pragma unroll
            for (int r = 0; r < 4; r++) ar[r] = alphap[quad * 4 + r];
            #pragma unroll
            for (int j = 0; j < 8; j++)
                #pragma unroll
                for (int r = 0; r < 4; r++) acc[j][r] *= ar[r];
            bf16x8 pf = *(const bf16x8*)&Pb[lm * 40 + quad * 8];
            #pragma unroll
            for (int j = 0; j < 8; j++) {
                int d = wave * 128 + j * 16 + lm;
                bf16x8 vf = *(const bf16x8*)&Vt[d * 32 + ((quad ^ (d & 3)) << 3)];
                acc[j] = __builtin_amdgcn_mfma_f32_16x16x32_bf16(pf, vf, acc[j], 0, 0, 0);
            }
            __syncthreads();
        }
    }
    float li[4];
    #pragma unroll
    for (int r = 0; r < 4; r++) li[r] = linv[quad * 4 + r];
    #pragma unroll
    for (int j = 0; j < 8; j++) {
        int d = wave * 128 + j * 16 + lm;
        #pragma unroll
        for (int r = 0; r < 4; r++)
            ctx[(rowq0 + quad * 4 + r) * DIMD + d] = f2bf(acc[j][r] * li[r]);
    }
}

// ---------------------------------------------------------------------------
extern "C" void kernel_launch(void* const* d_in, const int* in_sizes, int n_in,
                              void* d_out, int out_size, void* d_ws, size_t ws_size,
                              hipStream_t stream) {
    const float* query  = (const float*)d_in[0];
    const float* source = (const float*)d_in[1];
    const float* ctx0   = (const float*)d_in[2];
    const float* ctx1   = (const float*)d_in[3];
    // d_in[4] = mask: structurally known local window, unused
    const float* qn_g  = (const float*)d_in[5];
    const float* qn_b  = (const float*)d_in[6];
    const float* kvn_g = (const float*)d_in[7];
    const float* kvn_b = (const float*)d_in[8];
    const float* Wq = (const float*)d_in[9];   const float* bq = (const float*)d_in[10];
    const float* Wk = (const float*)d_in[11];  const float* bk = (const float*)d_in[12];
    const float* Wv = (const float*)d_in[13];  const float* bv = (const float*)d_in[14];
    const float* Wo = (const float*)d_in[15];  const float* bo = (const float*)d_in[16];
    const float* Wgq = (const float*)d_in[17];
    const float* Wgk = (const float*)d_in[18];
    const float* Wc0 = (const float*)d_in[19]; const float* bc0 = (const float*)d_in[20];
    const float* Wc1 = (const float*)d_in[21]; const float* bc1 = (const float*)d_in[22];
    const float* Wf  = (const float*)d_in[23]; const float* bfv = (const float*)d_in[24];

    // ---- workspace layout ----
    float* ws = (float*)d_ws;
    float* h      = ws;                         // 4096
    float* gamma  = h + 4096;                   // 4096
    float* beta   = gamma + 4096;               // 4096
    float* biaskv = beta + 4096;                // 1152
    float* biasq  = biaskv + 1152;              // 640
    float* mu_q   = biasq + 640;                // 8192
    float* rs_q   = mu_q + 8192;                // 8192
    u16* u = (u16*)(rs_q + 8192);
    u16* sln  = u;                 u += (long)MK * DIMD;   // LN(source) bf16
    u16* kp   = u;                 u += (long)MK * DIMD;   // k proj bf16
    u16* vp   = u;                 u += (long)MK * DIMD;   // v proj bf16
    u16* gk   = u;                 u += (long)MK * RANK;   // gate_k bf16
    u16* gq   = u;                 u += (long)MQ * RANK;   // gate_q bf16
    u16* qp   = u;                 u += (long)MQ * DIMD;   // q proj bf16
    u16* ctxb = u;                 u += (long)MQ * DIMD;   // attention output bf16
    u16* Btkv = u;                 u += 1152L * DIMD;      // [Wk^T | Wv^T | (Wk·Wgk)^T]
    u16* Btq  = u;                 u += 640L * DIMD;       // [Wq^T | (Wq·Wgq)^T]
    u16* Bto  = u;                 u += 512L * DIMD;       // Wo^T
    float* out = (float*)d_out;

    // K1: fused prep (latency bodies first, streaming last, HW-pipelined streams)
    prep_kernel<<<PREP_TOTAL, 256, 0, stream>>>(
        source, kvn_g, kvn_b, sln,
        query, mu_q, rs_q,
        ctx0, ctx1, Wc0, bc0, Wc1, bc1, h,
        Wk, Wv, Wq, Wo, Btkv, Btq, Bto,
        Wgk, Wgq, bk, bv, bq, biaskv, biasq);

    // K2: film_gb + kv projection GEMM
    kv_kernel<<<64 + 2304, 256, 0, stream>>>(
        h, Wf, bfv, gamma, beta, sln, Btkv, biaskv, kp, vp, gk);

    // K3: q projection GEMM (LN+FiLM inline)
    qproj_kernel<<<320, 256, 0, stream>>>(
        query, mu_q, rs_q, qn_g, qn_b, gamma, beta, Btq, biasq, qp, gq);

    // K4: flash local attention
    attn_kernel<<<BATCH * QS, 256, 0, stream>>>(qp, kp, vp, gq, gk, ctxb);

    // K5: output projection (fp32 out)
    ogemm_kernel<<<256, 256, 0, stream>>>(ctxb, Bto, bo, out);
}